// Round 5
// baseline (1460.840 us; speedup 1.0000x reference)
//
#include <hip/hip_runtime.h>
#include <hip/hip_bf16.h>
#include <math.h>

// Problem constants
#define N_ 8
#define S_ 1024
#define F_ 64
#define E_ 512
#define H_ 8
#define O_ 64
#define L_ 6
#define HD_ 64
#define FF_ 2048
#define SCALE_ 0.044194173824159216f   // 1/sqrt(E) -- module scales by sqrt(embed_size)
#define LOG2E_ 1.4426950408889634f
#define QSCALE_ (SCALE_ * LOG2E_)      // folded into Q at projection time

typedef unsigned short u16;
typedef __attribute__((ext_vector_type(4))) unsigned short u16x4;
typedef __attribute__((ext_vector_type(8))) unsigned short u16x8;
typedef __attribute__((ext_vector_type(8))) short short8;
typedef __attribute__((ext_vector_type(4))) float floatx4;

__device__ __forceinline__ u16 f2b(float f) {          // RNE (weights, one-time)
    union { float f; unsigned u; } v; v.f = f;
    unsigned u = v.u;
    unsigned r = (u + 0x7FFFu + ((u >> 16) & 1u)) >> 16;
    return (u16)r;
}
__device__ __forceinline__ u16 f2b_fast(float f) {     // round-nearest, 2 ops
    union { float f; unsigned u; } v; v.f = f;
    return (u16)((v.u + 0x8000u) >> 16);
}
__device__ __forceinline__ float b2f(u16 h) {
    union { unsigned u; float f; } v; v.u = ((unsigned)h) << 16;
    return v.f;
}

// async global->LDS, 16B per lane. LDS dest is wave-uniform base + lane*16.
__device__ __forceinline__ void gload16(const u16* g, u16* l) {
    __builtin_amdgcn_global_load_lds(
        (const __attribute__((address_space(1))) void*)g,
        (__attribute__((address_space(3))) void*)l, 16, 0, 0);
}

// ---------------------------------------------------------------------------
// MFMA first projection: h = relu(x^T W + b) + pos -> bf16 residual stream.
__global__ __launch_bounds__(256) void first_mfma(
    const float* __restrict__ x, const u16* __restrict__ wt,
    const float* __restrict__ bf, const float* __restrict__ pe,
    u16* __restrict__ resb)
{
    __shared__ u16 a_s[128][72];
    int t = threadIdx.x;
    int w = t >> 6, lane = t & 63, quad = lane >> 4, c16 = lane & 15;
    int rowhalf = w >> 1, colhalf = w & 1;
    int col0 = blockIdx.x * 128;
    int row0 = blockIdx.y * 128;          // n*S + s0 (never crosses n)
    int n = row0 >> 10, s0 = row0 & 1023;

    const float* xb = x + (size_t)n * F_ * S_ + s0;
    #pragma unroll
    for (int i = 0; i < 8; i++) {
        int pos = (t + i * 256) * 4;      // 8192 elems, f-major
        int f = pos >> 7, sl = pos & 127;
        float4 v = *(const float4*)&xb[(size_t)f * S_ + sl];
        a_s[sl + 0][f] = f2b_fast(v.x);
        a_s[sl + 1][f] = f2b_fast(v.y);
        a_s[sl + 2][f] = f2b_fast(v.z);
        a_s[sl + 3][f] = f2b_fast(v.w);
    }
    __syncthreads();

    floatx4 acc[4][4];
    #pragma unroll
    for (int mt = 0; mt < 4; mt++)
        #pragma unroll
        for (int nt = 0; nt < 4; nt++) acc[mt][nt] = (floatx4){0.f, 0.f, 0.f, 0.f};

    #pragma unroll
    for (int ks = 0; ks < 2; ks++) {
        short8 af[4], bfr[4];
        #pragma unroll
        for (int mt = 0; mt < 4; mt++)
            af[mt] = *(const short8*)&a_s[rowhalf * 64 + mt * 16 + c16][ks * 32 + quad * 8];
        #pragma unroll
        for (int nt = 0; nt < 4; nt++)
            bfr[nt] = *(const short8*)&wt[(size_t)(col0 + colhalf * 64 + nt * 16 + c16) * F_
                                          + ks * 32 + quad * 8];
        #pragma unroll
        for (int mt = 0; mt < 4; mt++)
            #pragma unroll
            for (int nt = 0; nt < 4; nt++)
                acc[mt][nt] = __builtin_amdgcn_mfma_f32_16x16x32_bf16(
                    af[mt], bfr[nt], acc[mt][nt], 0, 0, 0);
    }

    #pragma unroll
    for (int nt = 0; nt < 4; nt++) {
        int col = col0 + colhalf * 64 + nt * 16 + c16;
        float bv = bf[col];
        #pragma unroll
        for (int mt = 0; mt < 4; mt++) {
            #pragma unroll
            for (int r = 0; r < 4; r++) {
                size_t row = (size_t)row0 + rowhalf * 64 + mt * 16 + quad * 4 + r;
                int s = (int)(row & 1023);
                float v = fmaxf(acc[mt][nt][r] + bv, 0.f) + pe[(size_t)s * E_ + col];
                resb[row * E_ + col] = f2b_fast(v);
            }
        }
    }
}

// ---------------------------------------------------------------------------
// ONE-launch weight prep: all cast+transposes + qkv weights, dispatched by
// blockIdx range. Replaces 6 separate launches.
__global__ __launch_bounds__(256) void wprep(
    const float* __restrict__ W_first, const float* __restrict__ Wo,
    const float* __restrict__ Wf1, const float* __restrict__ Wf2,
    const float* __restrict__ Wfin,
    const float* __restrict__ Wq, const float* __restrict__ Wk,
    const float* __restrict__ Wv,
    u16* __restrict__ w1t, u16* __restrict__ wot, u16* __restrict__ wf1t,
    u16* __restrict__ wf2t, u16* __restrict__ wft,
    u16* __restrict__ wqt, u16* __restrict__ wkt, u16* __restrict__ wvt)
{
    int b = blockIdx.x;
    int t = threadIdx.x;
    __shared__ float tile[32][33];
    const float* W; u16* Wt; int K, Nc, bx, by;
    if (b < 32) {                         // W_first: K=64, Nc=512
        W = W_first; Wt = w1t; K = F_; Nc = E_; bx = b & 15; by = b >> 4;
    } else if (b < 32 + 1536) {           // Wo x6: K=512, Nc=512
        int i = b - 32; int z = i >> 8; int r = i & 255;
        W = Wo + (size_t)z * E_ * E_; Wt = wot + (size_t)z * E_ * E_;
        K = E_; Nc = E_; bx = r & 15; by = r >> 4;
    } else if (b < 32 + 1536 + 6144) {    // Wf1 x6: K=512, Nc=2048
        int i = b - (32 + 1536); int z = i >> 10; int r = i & 1023;
        W = Wf1 + (size_t)z * E_ * FF_; Wt = wf1t + (size_t)z * E_ * FF_;
        K = E_; Nc = FF_; bx = r & 63; by = r >> 6;
    } else if (b < 32 + 1536 + 12288) {   // Wf2 x6: K=2048, Nc=512
        int i = b - (32 + 1536 + 6144); int z = i >> 10; int r = i & 1023;
        W = Wf2 + (size_t)z * FF_ * E_; Wt = wf2t + (size_t)z * FF_ * E_;
        K = FF_; Nc = E_; bx = r & 15; by = r >> 4;
    } else if (b < 32 + 1536 + 12288 + 32) { // Wfin: K=512, Nc=64
        int r = b - (32 + 1536 + 12288);
        W = Wfin; Wt = wft; K = E_; Nc = O_; bx = r & 1; by = r >> 1;
    } else {                              // qkv weights: 6 blocks (1/layer)
        int l = b - (32 + 1536 + 12288 + 32);
        size_t off = (size_t)l * HD_ * HD_;
        #pragma unroll
        for (int i = 0; i < 16; i++) {
            int idx = t + i * 256;        // = e*64 + d
            int e = idx >> 6, d = idx & 63;
            wqt[off + idx] = f2b(Wq[off + d * HD_ + e]);
            wkt[off + idx] = f2b(Wk[off + d * HD_ + e]);
            wvt[off + idx] = f2b(Wv[off + d * HD_ + e]);
        }
        return;
    }
    #pragma unroll
    for (int i = 0; i < 4; i++) {
        int q = t + i * 256; int r = q >> 5, c = q & 31;
        tile[r][c] = W[(size_t)(by * 32 + r) * Nc + bx * 32 + c];
    }
    __syncthreads();
    #pragma unroll
    for (int i = 0; i < 4; i++) {
        int q = t + i * 256; int r = q >> 5, c = q & 31;
        Wt[(size_t)(bx * 32 + r) * K + by * 32 + c] = f2b(tile[c][r]);
    }
}

// ---------------------------------------------------------------------------
// MFMA fused qkv; Q pre-scaled by QSCALE_; V written DIRECTLY transposed
// (N,H,D,S) via LDS re-transpose. A-fragments read DIRECT from global
// (rows are 128B -> L1/L2-served; no LDS staging, no initial barrier).
__global__ __launch_bounds__(256) void qkv_mfma(
    const u16* __restrict__ hb,
    const u16* __restrict__ wqt, const u16* __restrict__ wkt,
    const u16* __restrict__ wvt,
    const float* __restrict__ bq, const float* __restrict__ bk,
    const float* __restrict__ bvp,
    u16* __restrict__ qo, u16* __restrict__ ko, u16* __restrict__ vt)
{
    __shared__ u16 vt_s[128 * 64];       // only for the V transpose
    int t = threadIdx.x;
    int w = t >> 6, lane = t & 63, quad = lane >> 4, c16 = lane & 15;
    size_t row0 = (size_t)blockIdx.x * 128;

    short8 af[2][2];
    #pragma unroll
    for (int mt = 0; mt < 2; mt++)
        #pragma unroll
        for (int ks = 0; ks < 2; ks++)
            af[mt][ks] = *(const short8*)&hb[(row0 + w * 32 + mt * 16 + c16) * HD_
                                             + ks * 32 + quad * 8];

    // ---- Q (m=0) and K (m=1): normal row-major stores --------------------
    const u16* wts[2] = {wqt, wkt};
    const float* bs[2] = {bq, bk};
    u16* outs[2] = {qo, ko};
    #pragma unroll
    for (int m = 0; m < 2; m++) {
        short8 bfr[4][2];
        #pragma unroll
        for (int nt = 0; nt < 4; nt++)
            #pragma unroll
            for (int ks = 0; ks < 2; ks++)
                bfr[nt][ks] = *(const short8*)&wts[m][(nt * 16 + c16) * HD_ + ks * 32 + quad * 8];
        floatx4 acc[2][4];
        #pragma unroll
        for (int mt = 0; mt < 2; mt++)
            #pragma unroll
            for (int nt = 0; nt < 4; nt++) acc[mt][nt] = (floatx4){0.f, 0.f, 0.f, 0.f};
        #pragma unroll
        for (int ks = 0; ks < 2; ks++)
            #pragma unroll
            for (int mt = 0; mt < 2; mt++)
                #pragma unroll
                for (int nt = 0; nt < 4; nt++)
                    acc[mt][nt] = __builtin_amdgcn_mfma_f32_16x16x32_bf16(
                        af[mt][ks], bfr[nt][ks], acc[mt][nt], 0, 0, 0);
        float osc = (m == 0) ? QSCALE_ : 1.0f;
        #pragma unroll
        for (int nt = 0; nt < 4; nt++) {
            float bv_ = bs[m][nt * 16 + c16];
            #pragma unroll
            for (int mt = 0; mt < 2; mt++)
                #pragma unroll
                for (int r = 0; r < 4; r++)
                    outs[m][(row0 + w * 32 + mt * 16 + quad * 4 + r) * HD_ + nt * 16 + c16] =
                        f2b_fast((acc[mt][nt][r] + bv_) * osc);
        }
    }

    // ---- V (m=2): compute, then transpose via LDS to (N,H,D,S) -----------
    {
        short8 bfr[4][2];
        #pragma unroll
        for (int nt = 0; nt < 4; nt++)
            #pragma unroll
            for (int ks = 0; ks < 2; ks++)
                bfr[nt][ks] = *(const short8*)&wvt[(nt * 16 + c16) * HD_ + ks * 32 + quad * 8];
        floatx4 acc[2][4];
        #pragma unroll
        for (int mt = 0; mt < 2; mt++)
            #pragma unroll
            for (int nt = 0; nt < 4; nt++) acc[mt][nt] = (floatx4){0.f, 0.f, 0.f, 0.f};
        #pragma unroll
        for (int ks = 0; ks < 2; ks++)
            #pragma unroll
            for (int mt = 0; mt < 2; mt++)
                #pragma unroll
                for (int nt = 0; nt < 4; nt++)
                    acc[mt][nt] = __builtin_amdgcn_mfma_f32_16x16x32_bf16(
                        af[mt][ks], bfr[nt][ks], acc[mt][nt], 0, 0, 0);

        #pragma unroll
        for (int nt = 0; nt < 4; nt++) {
            float bv_ = bvp[nt * 16 + c16];
            #pragma unroll
            for (int mt = 0; mt < 2; mt++)
                #pragma unroll
                for (int r = 0; r < 4; r++) {
                    int fr = w * 32 + mt * 16 + quad * 4 + r;   // flat row in block
                    int h = fr & 7, sl = fr >> 3;
                    vt_s[((h * 64 + nt * 16 + c16) * 16) + sl] =
                        f2b_fast(acc[mt][nt][r] + bv_);
                }
        }
        __syncthreads();
        int sflat0 = (int)(row0 >> 3);   // 16-aligned; same n for whole block
        int n = sflat0 >> 10, sbase = sflat0 & 1023;
        #pragma unroll
        for (int i = 0; i < 4; i++) {
            int u = t + i * 256;         // 1024 units of 16B
            int h = u >> 7, rest = u & 127, d = rest >> 1, half = rest & 1;
            *(u16x8*)&vt[((size_t)((n * 8 + h) * 64 + d)) * (size_t)S_ + sbase + half * 8] =
                *(u16x8*)&vt_s[(h * 64 + d) * 16 + half * 8];
        }
    }
}

// ---------------------------------------------------------------------------
// MFMA flash attention, de-staged: K/V/Q fragments read DIRECT from global
// (fragment pattern = rows mt*16+c16, 16B at ks*32+quad*8 -> L1/L2-served;
// K-tile 8KB + V-tile 8KB fit L1; chunked bid swizzle keeps each (n,h) on
// one XCD's L2). LDS holds ONLY wave-private P strips (8KB) -> ZERO barriers
// in the k-loop; waves free-run and the compiler pipelines across tiles.
// Same MFMA order as before -> bitwise-identical output.
__global__ __launch_bounds__(256, 4) void attn_mfma(
    const u16* __restrict__ Q, const u16* __restrict__ K,
    const u16* __restrict__ Vt, u16* __restrict__ O)
{
    int bid0 = blockIdx.x;               // 1024 = N*H*(S/64)
    int bid = (bid0 & 7) * 128 + (bid0 >> 3);   // chunked XCD swizzle
    int qt = bid & 15, hh = (bid >> 4) & 7, n = bid >> 7;
    int t = threadIdx.x;
    int w = t >> 6, lane = t & 63, quad = lane >> 4, c16 = lane & 15;

    __shared__ u16 p_all[4 * 16 * 64];   // per-wave 16-row P strips
    u16* p_s = p_all + w * 16 * 64;      // wave-private, [q_local][key]

    const size_t qkbase = (size_t)n * S_ * E_ + hh * 64;
    const size_t vtbase = ((size_t)(n * H_ + hh) * 64) * (size_t)S_;

    // Q fragments direct from global (B-operand of S^T): q row w*16 + c16
    short8 qf[2];
    #pragma unroll
    for (int ks = 0; ks < 2; ks++)
        qf[ks] = *(const short8*)&Q[qkbase + (size_t)(qt * 64 + w * 16 + c16) * E_
                                    + ks * 32 + quad * 8];

    // per-lane fragment base pointers
    const u16* kp = K + qkbase + (size_t)c16 * E_ + quad * 8;
    const u16* vp = Vt + vtbase + (size_t)c16 * S_ + quad * 8;

    const short8 ones = {(short)0x3F80, (short)0x3F80, (short)0x3F80, (short)0x3F80,
                         (short)0x3F80, (short)0x3F80, (short)0x3F80, (short)0x3F80};

    floatx4 oaccT[4];                    // [d-tile]: O^T[d][q]
    floatx4 lacc = (floatx4){0.f, 0.f, 0.f, 0.f};
    #pragma unroll
    for (int mt = 0; mt < 4; mt++) oaccT[mt] = (floatx4){0.f, 0.f, 0.f, 0.f};

    for (int k0 = 0; k0 < S_; k0 += 64) {
        // K fragments direct (A-operand of S^T): key rows k0+mt*16+c16
        short8 kf[2][4];
        #pragma unroll
        for (int ks = 0; ks < 2; ks++)
            #pragma unroll
            for (int mt = 0; mt < 4; mt++)
                kf[ks][mt] = *(const short8*)&kp[(size_t)(k0 + mt * 16) * E_ + ks * 32];

        // S^T = K Q^T : st[mt], lane holds S[q=c16][key=mt*16+quad*4+r]
        floatx4 st[4];
        #pragma unroll
        for (int mt = 0; mt < 4; mt++) st[mt] = (floatx4){0.f, 0.f, 0.f, 0.f};
        __builtin_amdgcn_s_setprio(1);
        #pragma unroll
        for (int ks = 0; ks < 2; ks++)
            #pragma unroll
            for (int mt = 0; mt < 4; mt++)
                st[mt] = __builtin_amdgcn_mfma_f32_16x16x32_bf16(
                    kf[ks][mt], qf[ks], st[mt], 0, 0, 0);
        __builtin_amdgcn_s_setprio(0);

        // V^T fragments direct (A-operand of O^T): d rows mt*16+c16
        // issued here so HBM/L2 latency hides under the exp2/pack VALU.
        short8 vf[2][4];
        #pragma unroll
        for (int ks = 0; ks < 2; ks++)
            #pragma unroll
            for (int mt = 0; mt < 4; mt++)
                vf[ks][mt] = *(const short8*)&vp[(size_t)(mt * 16) * S_ + k0 + ks * 32];

        // P = exp2(S^T), pack 4 keys -> one b64 swizzled LDS write per mt
        #pragma unroll
        for (int mt = 0; mt < 4; mt++) {
            u16x4 h;
            #pragma unroll
            for (int r = 0; r < 4; r++) h[r] = f2b_fast(exp2f(st[mt][r]));
            *(u16x4*)&p_s[c16 * 64 + (((2 * mt + (quad >> 1)) ^ (c16 & 7)) * 8)
                          + (quad & 1) * 4] = h;
        }

        // O^T += V^T P^T ; l += ones . P^T   (p_s wave-private: no barrier)
        __builtin_amdgcn_s_setprio(1);
        #pragma unroll
        for (int ks = 0; ks < 2; ks++) {
            short8 pf = *(const short8*)&p_s[c16 * 64 + (((ks * 4 + quad) ^ (c16 & 7)) * 8)];
            lacc = __builtin_amdgcn_mfma_f32_16x16x32_bf16(ones, pf, lacc, 0, 0, 0);
            #pragma unroll
            for (int mt = 0; mt < 4; mt++)
                oaccT[mt] = __builtin_amdgcn_mfma_f32_16x16x32_bf16(
                    vf[ks][mt], pf, oaccT[mt], 0, 0, 0);
        }
        __builtin_amdgcn_s_setprio(0);
    }

    // epilogue: lane c16 owns q-row; 4 contiguous d per (mt) -> 8B stores
    {
        float rl = 1.f / lacc[0];
        int s = qt * 64 + w * 16 + c16;
        size_t base = (size_t)(n * S_ + s) * E_ + hh * 64;
        #pragma unroll
        for (int mt = 0; mt < 4; mt++) {
            u16x4 h;
            #pragma unroll
            for (int r = 0; r < 4; r++) h[r] = f2b_fast(oaccT[mt][r] * rl);
            *(u16x4*)&O[base + mt * 16 + quad * 4] = h;
        }
    }
}

// ---------------------------------------------------------------------------
// MFMA GEMM, m97 structure: async global_load_lds (16B) staging into LINEAR
// LDS; ds_read swizzle via pre-swizzled global source (rule #21).
// Chunked XCD swizzle colocates same-A-panel blocks on one XCD's L2.
template <int MT, int NT, bool RELU, bool HASRES, bool OUTF32, bool OUTBF16>
__global__ __launch_bounds__(256, 2) void gemm_mfma(
    const u16* __restrict__ A, const u16* __restrict__ Bt,
    const float* __restrict__ bias, const u16* __restrict__ resid,
    float* __restrict__ outf, u16* __restrict__ outb, int M, int Nc, int K)
{
    constexpr int MFR = MT / 32;
    constexpr int NFR = NT / 32;
    constexpr int AI  = MT / 32;
    constexpr int BI  = NT / 32;
    __shared__ u16 a_s[MT * 64];
    __shared__ u16 b_s[NT * 64];

    int t = threadIdx.x;
    int w = t >> 6, lane = t & 63, quad = lane >> 4, c16 = lane & 15;
    int rw = w >> 1, cw = w & 1;

    int gx = gridDim.x;
    int nwg = gx * (int)gridDim.y;
    int lin = (int)blockIdx.y * gx + (int)blockIdx.x;
    int cpx = nwg >> 3;
    int id2 = (lin & 7) * cpx + (lin >> 3);
    int bx = id2 % gx, by = id2 / gx;

    size_t row0 = (size_t)by * MT;
    size_t col0 = (size_t)bx * NT;

    size_t aoff[AI]; int adst[AI];
    #pragma unroll
    for (int i = 0; i < AI; i++) {
        int p = t + i * 256;
        int r = p >> 3;
        int kc = (p & 7) ^ (r & 7);
        aoff[i] = (row0 + r) * (size_t)K + kc * 8;
        adst[i] = w * 512 + i * 2048;
    }
    size_t boff[BI]; int bdst[BI];
    #pragma unroll
    for (int i = 0; i < BI; i++) {
        int p = t + i * 256;
        int r = p >> 3;
        int kc = (p & 7) ^ (r & 7);
        boff[i] = (col0 + r) * (size_t)K + kc * 8;
        bdst[i] = w * 512 + i * 2048;
    }

    floatx4 acc[MFR][NFR];
    #pragma unroll
    for (int mt = 0; mt < MFR; mt++)
        #pragma unroll
        for (int nt = 0; nt < NFR; nt++) acc[mt][nt] = (floatx4){0.f, 0.f, 0.f, 0.f};

    for (int k0 = 0; k0 < K; k0 += 64) {
        #pragma unroll
        for (int i = 0; i < AI; i++) gload16(A + aoff[i] + k0, a_s + adst[i]);
        #pragma unroll
        for (int i = 0; i < BI; i++) gload16(Bt + boff[i] + k0, b_s + bdst[i]);
        __syncthreads();

        #pragma unroll
        for (int ks = 0; ks < 2; ks++) {
            short8 af[MFR], bfr[NFR];
            #pragma unroll
            for (int mt = 0; mt < MFR; mt++) {
                int r = rw * (MT / 2) + mt * 16 + c16;
                af[mt] = *(const short8*)&a_s[r * 64 + (((ks * 4 + quad) ^ (r & 7)) * 8)];
            }
            #pragma unroll
            for (int nt = 0; nt < NFR; nt++) {
                int r = cw * (NT / 2) + nt * 16 + c16;
                bfr[nt] = *(const short8*)&b_s[r * 64 + (((ks * 4 + quad) ^ (r & 7)) * 8)];
            }
            #pragma unroll
            for (int mt = 0; mt < MFR; mt++)
                #pragma unroll
                for (int nt = 0; nt < NFR; nt++)
                    acc[mt][nt] = __builtin_amdgcn_mfma_f32_16x16x32_bf16(
                        af[mt], bfr[nt], acc[mt][nt], 0, 0, 0);
        }
        __syncthreads();
    }

    #pragma unroll
    for (int nt = 0; nt < NFR; nt++) {
        int col = (int)col0 + cw * (NT / 2) + nt * 16 + c16;
        float bv = bias[col];
        #pragma unroll
        for (int mt = 0; mt < MFR; mt++) {
            size_t rowb = row0 + rw * (MT / 2) + mt * 16 + quad * 4;
            #pragma unroll
            for (int r = 0; r < 4; r++) {
                size_t row = rowb + r;
                float v = acc[mt][nt][r] + bv;
                if constexpr (HASRES) v += b2f(resid[row * Nc + col]);
                if constexpr (RELU) v = fmaxf(v, 0.f);
                if constexpr (OUTF32) outf[row * Nc + col] = v;
                if constexpr (OUTBF16) outb[row * Nc + col] = f2b_fast(v);
            }
        }
    }
}

// ---------------------------------------------------------------------------
// LayerNorm over E=512, one block per row; fp32 in, bf16 out.
__global__ __launch_bounds__(256) void layernorm_k(
    const float* __restrict__ in, const float* __restrict__ g,
    const float* __restrict__ bb, u16* __restrict__ outb)
{
    int row = blockIdx.x;
    int t = threadIdx.x;
    const float* x = in + (size_t)row * E_;
    float x0 = x[t], x1 = x[t + 256];
    float s = x0 + x1;
    #pragma unroll
    for (int off = 32; off; off >>= 1) s += __shfl_down(s, off, 64);
    __shared__ float red[4];
    int wid = t >> 6, lane = t & 63;
    if (lane == 0) red[wid] = s;
    __syncthreads();
    float m = (red[0] + red[1] + red[2] + red[3]) * (1.f / E_);
    float d0 = x0 - m, d1 = x1 - m;
    float sq = d0 * d0 + d1 * d1;
    #pragma unroll
    for (int off = 32; off; off >>= 1) sq += __shfl_down(sq, off, 64);
    __syncthreads();
    if (lane == 0) red[wid] = sq;
    __syncthreads();
    float var = (red[0] + red[1] + red[2] + red[3]) * (1.f / E_);
    float rstd = rsqrtf(var + 1e-5f);
    outb[(size_t)row * E_ + t] = f2b_fast(d0 * rstd * g[t] + bb[t]);
    outb[(size_t)row * E_ + t + 256] = f2b_fast(d1 * rstd * g[t + 256] + bb[t + 256]);
}

// ---------------------------------------------------------------------------
// MFMA final projection: out[n,o,s] = resb[n*S+s,:] @ Wfint[o,:] + bfin[o]
__global__ __launch_bounds__(256) void final_mfma(
    const u16* __restrict__ hb, const u16* __restrict__ wft,
    const float* __restrict__ bfin, float* __restrict__ outp)
{
    __shared__ u16 a_s[64][72];
    int t = threadIdx.x;
    int w = t >> 6, lane = t & 63, quad = lane >> 4, c16 = lane & 15;
    size_t row0 = (size_t)blockIdx.x * 64;

    floatx4 acc[4];
    #pragma unroll
    for (int nt = 0; nt < 4; nt++) acc[nt] = (floatx4){0.f, 0.f, 0.f, 0.f};

    int ar = t >> 3, acq = (t & 7) * 8;
    u16x8 pa[2];
    #pragma unroll
    for (int i = 0; i < 2; i++)
        pa[i] = *(const u16x8*)&hb[(row0 + ar + i * 32) * E_ + acq];

    for (int k0 = 0; k0 < E_; k0 += 64) {
        #pragma unroll
        for (int i = 0; i < 2; i++)
            *(u16x8*)&a_s[ar + i * 32][acq] = pa[i];
        __syncthreads();
        if (k0 + 64 < E_) {
            #pragma unroll
            for (int i = 0; i < 2; i++)
                pa[i] = *(const u16x8*)&hb[(row0 + ar + i * 32) * E_ + k0 + 64 + acq];
        }
        #pragma unroll
        for (int ks = 0; ks < 2; ks++) {
            short8 af = *(const short8*)&a_s[w * 16 + c16][ks * 32 + quad * 8];
            #pragma unroll
            for (int nt = 0; nt < 4; nt++) {
                short8 bf = *(const short8*)&wft[(nt * 16 + c16) * E_ + k0 + ks * 32 + quad * 8];
                acc[nt] = __builtin_amdgcn_mfma_f32_16x16x32_bf16(af, bf, acc[nt], 0, 0, 0);
            }
        }
        __syncthreads();
    }

    #pragma unroll
    for (int nt = 0; nt < 4; nt++) {
        int o = nt * 16 + c16;
        float bv = bfin[o];
        #pragma unroll
        for (int r = 0; r < 4; r++) {
            size_t row = row0 + w * 16 + quad * 4 + r;    // n*S + s
            int n = (int)(row >> 10), s = (int)(row & 1023);
            outp[((size_t)(n * O_ + o)) * S_ + s] = acc[nt][r] + bv;
        }
    }
}

// ---------------------------------------------------------------------------
extern "C" void kernel_launch(void* const* d_in, const int* in_sizes, int n_in,
                              void* d_out, int out_size, void* d_ws, size_t ws_size,
                              hipStream_t stream)
{
    const float* x       = (const float*)d_in[0];
    const float* W_first = (const float*)d_in[1];
    const float* b_first = (const float*)d_in[2];
    const float* pos_emb = (const float*)d_in[3];
    const float* Wq      = (const float*)d_in[4];
    const float* bq      = (const float*)d_in[5];
    const float* Wk      = (const float*)d_in[6];
    const float* bk      = (const float*)d_in[7];
    const float* Wv      = (const float*)d_in[8];
    const float* bv      = (const float*)d_in[9];
    const float* Wo      = (const float*)d_in[10];
    const float* bo      = (const float*)d_in[11];
    const float* g1      = (const float*)d_in[12];
    const float* be1     = (const float*)d_in[13];
    const float* Wf1     = (const float*)d_in[14];
    const float* bf1     = (const float*)d_in[15];
    const float* Wf2     = (const float*)d_in[16];
    const float* bf2     = (const float*)d_in[17];
    const float* g2      = (const float*)d_in[18];
    const float* be2     = (const float*)d_in[19];
    const float* Wfin    = (const float*)d_in[20];
    const float* bfin    = (const float*)d_in[21];
    float* out = (float*)d_out;

    const size_t M4 = (size_t)N_ * S_ * E_;       // 4,194,304
    float* t1   = (float*)d_ws;                   // fp32 LN input
    u16*   resb = (u16*)(t1 + M4);                // bf16 residual stream (h/hx)
    u16*   qb   = resb + M4;
    u16*   kb   = qb + M4;
    u16*   vt   = kb + M4;
    u16*   ob   = vt + M4;
    u16*   ffb  = qb;                             // alias qb..ob (4*M4 = 32MB)
    u16*   wot  = ob + M4;                        // 6 * 512*512
    u16*   wf1t = wot + (size_t)L_ * E_ * E_;     // 6 * 2048*512 (as [FF][E])
    u16*   wf2t = wf1t + (size_t)L_ * E_ * FF_;   // 6 * 512*2048 (as [E][FF])
    u16*   wqt  = wf2t + (size_t)L_ * FF_ * E_;   // 6 * 64*64
    u16*   wkt  = wqt + (size_t)L_ * HD_ * HD_;
    u16*   wvt  = wkt + (size_t)L_ * HD_ * HD_;
    u16*   wft  = wvt + (size_t)L_ * HD_ * HD_;   // 64*512  (Wfin as [O][E])
    u16*   w1t  = wft + (size_t)O_ * E_;          // 512*64  (W_first as [E][F])

    const int rows = N_ * S_;                     // 8192

    wprep<<<32 + 1536 + 12288 + 32 + 6, 256, 0, stream>>>(
        W_first, Wo, Wf1, Wf2, Wfin, Wq, Wk, Wv,
        w1t, wot, wf1t, wf2t, wft, wqt, wkt, wvt);

    first_mfma<<<dim3(E_ / 128, rows / 128), 256, 0, stream>>>(
        x, w1t, b_first, pos_emb, resb);

    for (int i = 0; i < L_; i++) {
        qkv_mfma<<<512, 256, 0, stream>>>(
            resb, wqt + (size_t)i * HD_ * HD_, wkt + (size_t)i * HD_ * HD_,
            wvt + (size_t)i * HD_ * HD_, bq + i * HD_, bk + i * HD_, bv + i * HD_,
            qb, kb, vt);
        attn_mfma<<<1024, 256, 0, stream>>>(qb, kb, vt, ob);
        // t1 = ob @ Wo + bo + resb(h)
        gemm_mfma<128, 64, false, true, true, false><<<dim3(E_ / 64, rows / 128), 256, 0, stream>>>(
            ob, wot + (size_t)i * E_ * E_, bo + i * E_, resb, t1, nullptr, rows, E_, E_);
        layernorm_k<<<rows, 256, 0, stream>>>(t1, g1 + i * E_, be1 + i * E_, resb);
        // ffb = relu(resb(hx) @ Wf1 + bf1)
        gemm_mfma<128, 128, true, false, false, true><<<dim3(FF_ / 128, rows / 128), 256, 0, stream>>>(
            resb, wf1t + (size_t)i * E_ * FF_, bf1 + i * FF_, nullptr, nullptr, ffb,
            rows, FF_, E_);
        // t1 = ffb @ Wf2 + bf2 + resb(hx)
        gemm_mfma<128, 64, false, true, true, false><<<dim3(E_ / 64, rows / 128), 256, 0, stream>>>(
            ffb, wf2t + (size_t)i * FF_ * E_, bf2 + i * E_, resb, t1, nullptr,
            rows, E_, FF_);
        layernorm_k<<<rows, 256, 0, stream>>>(t1, g2 + i * E_, be2 + i * E_, resb);
    }

    final_mfma<<<rows / 64, 256, 0, stream>>>(resb, wft, bfin, out);
}

// Round 6
// 991.306 us; speedup vs baseline: 1.4737x; 1.4737x over previous
//
#include <hip/hip_runtime.h>
#include <hip/hip_bf16.h>
#include <math.h>

// Problem constants
#define N_ 8
#define S_ 1024
#define F_ 64
#define E_ 512
#define H_ 8
#define O_ 64
#define L_ 6
#define HD_ 64
#define FF_ 2048
#define SCALE_ 0.044194173824159216f   // 1/sqrt(E) -- module scales by sqrt(embed_size)
#define LOG2E_ 1.4426950408889634f
#define QSCALE_ (SCALE_ * LOG2E_)      // folded into Q at projection time

typedef unsigned short u16;
typedef __attribute__((ext_vector_type(4))) unsigned short u16x4;
typedef __attribute__((ext_vector_type(8))) unsigned short u16x8;
typedef __attribute__((ext_vector_type(8))) short short8;
typedef __attribute__((ext_vector_type(4))) float floatx4;

__device__ __forceinline__ u16 f2b(float f) {          // RNE (weights, one-time)
    union { float f; unsigned u; } v; v.f = f;
    unsigned u = v.u;
    unsigned r = (u + 0x7FFFu + ((u >> 16) & 1u)) >> 16;
    return (u16)r;
}
__device__ __forceinline__ u16 f2b_fast(float f) {     // round-nearest, 2 ops
    union { float f; unsigned u; } v; v.f = f;
    return (u16)((v.u + 0x8000u) >> 16);
}
__device__ __forceinline__ float b2f(u16 h) {
    union { unsigned u; float f; } v; v.u = ((unsigned)h) << 16;
    return v.f;
}

// async global->LDS, 16B per lane. LDS dest is wave-uniform base + lane*16.
__device__ __forceinline__ void gload16(const u16* g, u16* l) {
    __builtin_amdgcn_global_load_lds(
        (const __attribute__((address_space(1))) void*)g,
        (__attribute__((address_space(3))) void*)l, 16, 0, 0);
}

// ---------------------------------------------------------------------------
// MFMA first projection: h = relu(x^T W + b) + pos -> bf16 residual stream.
__global__ __launch_bounds__(256) void first_mfma(
    const float* __restrict__ x, const u16* __restrict__ wt,
    const float* __restrict__ bf, const float* __restrict__ pe,
    u16* __restrict__ resb)
{
    __shared__ u16 a_s[128][72];
    int t = threadIdx.x;
    int w = t >> 6, lane = t & 63, quad = lane >> 4, c16 = lane & 15;
    int rowhalf = w >> 1, colhalf = w & 1;
    int col0 = blockIdx.x * 128;
    int row0 = blockIdx.y * 128;          // n*S + s0 (never crosses n)
    int n = row0 >> 10, s0 = row0 & 1023;

    const float* xb = x + (size_t)n * F_ * S_ + s0;
    #pragma unroll
    for (int i = 0; i < 8; i++) {
        int pos = (t + i * 256) * 4;      // 8192 elems, f-major
        int f = pos >> 7, sl = pos & 127;
        float4 v = *(const float4*)&xb[(size_t)f * S_ + sl];
        a_s[sl + 0][f] = f2b_fast(v.x);
        a_s[sl + 1][f] = f2b_fast(v.y);
        a_s[sl + 2][f] = f2b_fast(v.z);
        a_s[sl + 3][f] = f2b_fast(v.w);
    }
    __syncthreads();

    floatx4 acc[4][4];
    #pragma unroll
    for (int mt = 0; mt < 4; mt++)
        #pragma unroll
        for (int nt = 0; nt < 4; nt++) acc[mt][nt] = (floatx4){0.f, 0.f, 0.f, 0.f};

    #pragma unroll
    for (int ks = 0; ks < 2; ks++) {
        short8 af[4], bfr[4];
        #pragma unroll
        for (int mt = 0; mt < 4; mt++)
            af[mt] = *(const short8*)&a_s[rowhalf * 64 + mt * 16 + c16][ks * 32 + quad * 8];
        #pragma unroll
        for (int nt = 0; nt < 4; nt++)
            bfr[nt] = *(const short8*)&wt[(size_t)(col0 + colhalf * 64 + nt * 16 + c16) * F_
                                          + ks * 32 + quad * 8];
        #pragma unroll
        for (int mt = 0; mt < 4; mt++)
            #pragma unroll
            for (int nt = 0; nt < 4; nt++)
                acc[mt][nt] = __builtin_amdgcn_mfma_f32_16x16x32_bf16(
                    af[mt], bfr[nt], acc[mt][nt], 0, 0, 0);
    }

    #pragma unroll
    for (int nt = 0; nt < 4; nt++) {
        int col = col0 + colhalf * 64 + nt * 16 + c16;
        float bv = bf[col];
        #pragma unroll
        for (int mt = 0; mt < 4; mt++) {
            #pragma unroll
            for (int r = 0; r < 4; r++) {
                size_t row = (size_t)row0 + rowhalf * 64 + mt * 16 + quad * 4 + r;
                int s = (int)(row & 1023);
                float v = fmaxf(acc[mt][nt][r] + bv, 0.f) + pe[(size_t)s * E_ + col];
                resb[row * E_ + col] = f2b_fast(v);
            }
        }
    }
}

// ---------------------------------------------------------------------------
// ONE-launch weight prep: all cast+transposes + qkv weights, dispatched by
// blockIdx range. Replaces 6 separate launches.
__global__ __launch_bounds__(256) void wprep(
    const float* __restrict__ W_first, const float* __restrict__ Wo,
    const float* __restrict__ Wf1, const float* __restrict__ Wf2,
    const float* __restrict__ Wfin,
    const float* __restrict__ Wq, const float* __restrict__ Wk,
    const float* __restrict__ Wv,
    u16* __restrict__ w1t, u16* __restrict__ wot, u16* __restrict__ wf1t,
    u16* __restrict__ wf2t, u16* __restrict__ wft,
    u16* __restrict__ wqt, u16* __restrict__ wkt, u16* __restrict__ wvt)
{
    int b = blockIdx.x;
    int t = threadIdx.x;
    __shared__ float tile[32][33];
    const float* W; u16* Wt; int K, Nc, bx, by;
    if (b < 32) {                         // W_first: K=64, Nc=512
        W = W_first; Wt = w1t; K = F_; Nc = E_; bx = b & 15; by = b >> 4;
    } else if (b < 32 + 1536) {           // Wo x6: K=512, Nc=512
        int i = b - 32; int z = i >> 8; int r = i & 255;
        W = Wo + (size_t)z * E_ * E_; Wt = wot + (size_t)z * E_ * E_;
        K = E_; Nc = E_; bx = r & 15; by = r >> 4;
    } else if (b < 32 + 1536 + 6144) {    // Wf1 x6: K=512, Nc=2048
        int i = b - (32 + 1536); int z = i >> 10; int r = i & 1023;
        W = Wf1 + (size_t)z * E_ * FF_; Wt = wf1t + (size_t)z * E_ * FF_;
        K = E_; Nc = FF_; bx = r & 63; by = r >> 6;
    } else if (b < 32 + 1536 + 12288) {   // Wf2 x6: K=2048, Nc=512
        int i = b - (32 + 1536 + 6144); int z = i >> 10; int r = i & 1023;
        W = Wf2 + (size_t)z * FF_ * E_; Wt = wf2t + (size_t)z * FF_ * E_;
        K = FF_; Nc = E_; bx = r & 15; by = r >> 4;
    } else if (b < 32 + 1536 + 12288 + 32) { // Wfin: K=512, Nc=64
        int r = b - (32 + 1536 + 12288);
        W = Wfin; Wt = wft; K = E_; Nc = O_; bx = r & 1; by = r >> 1;
    } else {                              // qkv weights: 6 blocks (1/layer)
        int l = b - (32 + 1536 + 12288 + 32);
        size_t off = (size_t)l * HD_ * HD_;
        #pragma unroll
        for (int i = 0; i < 16; i++) {
            int idx = t + i * 256;        // = e*64 + d
            int e = idx >> 6, d = idx & 63;
            wqt[off + idx] = f2b(Wq[off + d * HD_ + e]);
            wkt[off + idx] = f2b(Wk[off + d * HD_ + e]);
            wvt[off + idx] = f2b(Wv[off + d * HD_ + e]);
        }
        return;
    }
    #pragma unroll
    for (int i = 0; i < 4; i++) {
        int q = t + i * 256; int r = q >> 5, c = q & 31;
        tile[r][c] = W[(size_t)(by * 32 + r) * Nc + bx * 32 + c];
    }
    __syncthreads();
    #pragma unroll
    for (int i = 0; i < 4; i++) {
        int q = t + i * 256; int r = q >> 5, c = q & 31;
        Wt[(size_t)(bx * 32 + r) * K + by * 32 + c] = f2b(tile[c][r]);
    }
}

// ---------------------------------------------------------------------------
// MFMA fused qkv; Q pre-scaled by QSCALE_; V written DIRECTLY transposed
// (N,H,D,S) via LDS re-transpose. A-fragments read DIRECT from global
// (rows are 128B, row-contiguous across lanes -> coalesced, L2-served).
__global__ __launch_bounds__(256) void qkv_mfma(
    const u16* __restrict__ hb,
    const u16* __restrict__ wqt, const u16* __restrict__ wkt,
    const u16* __restrict__ wvt,
    const float* __restrict__ bq, const float* __restrict__ bk,
    const float* __restrict__ bvp,
    u16* __restrict__ qo, u16* __restrict__ ko, u16* __restrict__ vt)
{
    __shared__ u16 vt_s[128 * 64];       // only for the V transpose
    int t = threadIdx.x;
    int w = t >> 6, lane = t & 63, quad = lane >> 4, c16 = lane & 15;
    size_t row0 = (size_t)blockIdx.x * 128;

    short8 af[2][2];
    #pragma unroll
    for (int mt = 0; mt < 2; mt++)
        #pragma unroll
        for (int ks = 0; ks < 2; ks++)
            af[mt][ks] = *(const short8*)&hb[(row0 + w * 32 + mt * 16 + c16) * HD_
                                             + ks * 32 + quad * 8];

    // ---- Q (m=0) and K (m=1): normal row-major stores --------------------
    const u16* wts[2] = {wqt, wkt};
    const float* bs[2] = {bq, bk};
    u16* outs[2] = {qo, ko};
    #pragma unroll
    for (int m = 0; m < 2; m++) {
        short8 bfr[4][2];
        #pragma unroll
        for (int nt = 0; nt < 4; nt++)
            #pragma unroll
            for (int ks = 0; ks < 2; ks++)
                bfr[nt][ks] = *(const short8*)&wts[m][(nt * 16 + c16) * HD_ + ks * 32 + quad * 8];
        floatx4 acc[2][4];
        #pragma unroll
        for (int mt = 0; mt < 2; mt++)
            #pragma unroll
            for (int nt = 0; nt < 4; nt++) acc[mt][nt] = (floatx4){0.f, 0.f, 0.f, 0.f};
        #pragma unroll
        for (int ks = 0; ks < 2; ks++)
            #pragma unroll
            for (int mt = 0; mt < 2; mt++)
                #pragma unroll
                for (int nt = 0; nt < 4; nt++)
                    acc[mt][nt] = __builtin_amdgcn_mfma_f32_16x16x32_bf16(
                        af[mt][ks], bfr[nt][ks], acc[mt][nt], 0, 0, 0);
        float osc = (m == 0) ? QSCALE_ : 1.0f;
        #pragma unroll
        for (int nt = 0; nt < 4; nt++) {
            float bv_ = bs[m][nt * 16 + c16];
            #pragma unroll
            for (int mt = 0; mt < 2; mt++)
                #pragma unroll
                for (int r = 0; r < 4; r++)
                    outs[m][(row0 + w * 32 + mt * 16 + quad * 4 + r) * HD_ + nt * 16 + c16] =
                        f2b_fast((acc[mt][nt][r] + bv_) * osc);
        }
    }

    // ---- V (m=2): compute, then transpose via LDS to (N,H,D,S) -----------
    {
        short8 bfr[4][2];
        #pragma unroll
        for (int nt = 0; nt < 4; nt++)
            #pragma unroll
            for (int ks = 0; ks < 2; ks++)
                bfr[nt][ks] = *(const short8*)&wvt[(nt * 16 + c16) * HD_ + ks * 32 + quad * 8];
        floatx4 acc[2][4];
        #pragma unroll
        for (int mt = 0; mt < 2; mt++)
            #pragma unroll
            for (int nt = 0; nt < 4; nt++) acc[mt][nt] = (floatx4){0.f, 0.f, 0.f, 0.f};
        #pragma unroll
        for (int ks = 0; ks < 2; ks++)
            #pragma unroll
            for (int mt = 0; mt < 2; mt++)
                #pragma unroll
                for (int nt = 0; nt < 4; nt++)
                    acc[mt][nt] = __builtin_amdgcn_mfma_f32_16x16x32_bf16(
                        af[mt][ks], bfr[nt][ks], acc[mt][nt], 0, 0, 0);

        #pragma unroll
        for (int nt = 0; nt < 4; nt++) {
            float bv_ = bvp[nt * 16 + c16];
            #pragma unroll
            for (int mt = 0; mt < 2; mt++)
                #pragma unroll
                for (int r = 0; r < 4; r++) {
                    int fr = w * 32 + mt * 16 + quad * 4 + r;   // flat row in block
                    int h = fr & 7, sl = fr >> 3;
                    vt_s[((h * 64 + nt * 16 + c16) * 16) + sl] =
                        f2b_fast(acc[mt][nt][r] + bv_);
                }
        }
        __syncthreads();
        int sflat0 = (int)(row0 >> 3);   // 16-aligned; same n for whole block
        int n = sflat0 >> 10, sbase = sflat0 & 1023;
        #pragma unroll
        for (int i = 0; i < 4; i++) {
            int u = t + i * 256;         // 1024 units of 16B
            int h = u >> 7, rest = u & 127, d = rest >> 1, half = rest & 1;
            *(u16x8*)&vt[((size_t)((n * 8 + h) * 64 + d)) * (size_t)S_ + sbase + half * 8] =
                *(u16x8*)&vt_s[(h * 64 + d) * 16 + half * 8];
        }
    }
}

// ---------------------------------------------------------------------------
// MFMA flash attention: QBLK=128 (2 q-fragments/wave amortize every K/V LDS
// read over 2 MFMAs -> halves LDS-read per MFMA vs QBLK=64), double-buffered
// K/V with ONE barrier per k-tile, XOR-swizzled stride-64 LDS, setprio,
// chunked bid swizzle (one batch-n per XCD's L2). Grid 512, 48KB LDS.
__global__ __launch_bounds__(256, 2) void attn_mfma(
    const u16* __restrict__ Q, const u16* __restrict__ K,
    const u16* __restrict__ Vt, u16* __restrict__ O)
{
    int bid0 = blockIdx.x;               // 512 = N*H*(S/128)
    int bid = (bid0 & 7) * 64 + (bid0 >> 3);    // chunked XCD swizzle
    int qt = bid & 7, hh = (bid >> 3) & 7, n = bid >> 6;
    int t = threadIdx.x;
    int w = t >> 6, lane = t & 63, quad = lane >> 4, c16 = lane & 15;

    __shared__ u16 qp_s[128 * 64];       // Q tile; P strips alias after hoist
    __shared__ u16 k_s[2][64 * 64];      // K rows (key, d), double-buffered
    __shared__ u16 vt_s[2][64 * 64];     // Vt rows (d, key), double-buffered
    u16* p_s = qp_s + w * 32 * 64;       // wave-private 32-row strip

    const size_t qkbase = (size_t)n * S_ * E_ + hh * 64;
    const size_t vtbase = ((size_t)(n * H_ + hh) * 64) * (size_t)S_;

    int ar = t >> 3, act = t & 7;        // 32 rows x 8 chunks per 256 threads
    int acq = act * 8;
    int scw[2];
    #pragma unroll
    for (int i = 0; i < 2; i++) scw[i] = ((act ^ ((ar + i * 32) & 7)) * 8);

    // Q staging (128 rows) + KV tile-0 register load
    #pragma unroll
    for (int i = 0; i < 4; i++) {
        int q = t + i * 256; int r = q >> 3, c = q & 7;
        *(u16x8*)&qp_s[r * 64 + ((c ^ (r & 7)) * 8)] =
            *(const u16x8*)&Q[qkbase + (size_t)(qt * 128 + r) * E_ + c * 8];
    }
    u16x8 pk[2], pv[2];
    #pragma unroll
    for (int i = 0; i < 2; i++) {
        pk[i] = *(const u16x8*)&K[qkbase + (size_t)(ar + i * 32) * E_ + acq];
        pv[i] = *(const u16x8*)&Vt[vtbase + (size_t)(ar + i * 32) * S_ + acq];
    }
    __syncthreads();                     // Q visible

    // hoist Q fragments (B-operand of S^T): rows w*32 + nq*16 + c16
    short8 qf[2][2];
    #pragma unroll
    for (int nq = 0; nq < 2; nq++)
        #pragma unroll
        for (int ks = 0; ks < 2; ks++) {
            int r = w * 32 + nq * 16 + c16;
            qf[nq][ks] = *(const short8*)&qp_s[r * 64 + (((ks * 4 + quad) ^ (r & 7)) * 8)];
        }

    // write tile 0 into buffer 0
    #pragma unroll
    for (int i = 0; i < 2; i++) {
        int r = ar + i * 32;
        *(u16x8*)&k_s[0][r * 64 + scw[i]] = pk[i];
        *(u16x8*)&vt_s[0][r * 64 + scw[i]] = pv[i];
    }
    __syncthreads();                     // tile 0 visible; all qf hoisted

    const short8 ones = {(short)0x3F80, (short)0x3F80, (short)0x3F80, (short)0x3F80,
                         (short)0x3F80, (short)0x3F80, (short)0x3F80, (short)0x3F80};

    floatx4 oaccT[4][2];                 // [d-tile][q-tile]: O^T[d][q]
    floatx4 lacc[2];
    #pragma unroll
    for (int nq = 0; nq < 2; nq++) {
        lacc[nq] = (floatx4){0.f, 0.f, 0.f, 0.f};
        #pragma unroll
        for (int mt = 0; mt < 4; mt++) oaccT[mt][nq] = (floatx4){0.f, 0.f, 0.f, 0.f};
    }

    for (int k0 = 0; k0 < S_; k0 += 64) {
        int cur = (k0 >> 6) & 1;
        const u16* ks_ = k_s[cur];
        const u16* vs_ = vt_s[cur];
        bool more = (k0 + 64 < S_);
        if (more) {                      // issue next-tile loads early
            #pragma unroll
            for (int i = 0; i < 2; i++) {
                pk[i] = *(const u16x8*)&K[qkbase + (size_t)(k0 + 64 + ar + i * 32) * E_ + acq];
                pv[i] = *(const u16x8*)&Vt[vtbase + (size_t)(ar + i * 32) * S_ + k0 + 64 + acq];
            }
        }

        // S^T = K Q^T : st[mt][nq], lane holds S[q=c16][key=mt*16+quad*4+r]
        floatx4 st[4][2];
        #pragma unroll
        for (int mt = 0; mt < 4; mt++)
            #pragma unroll
            for (int nq = 0; nq < 2; nq++) st[mt][nq] = (floatx4){0.f, 0.f, 0.f, 0.f};
        __builtin_amdgcn_s_setprio(1);
        #pragma unroll
        for (int ks = 0; ks < 2; ks++) {
            short8 kf[4];
            #pragma unroll
            for (int mt = 0; mt < 4; mt++) {
                int r = mt * 16 + c16;
                kf[mt] = *(const short8*)&ks_[r * 64 + (((ks * 4 + quad) ^ (r & 7)) * 8)];
            }
            #pragma unroll
            for (int mt = 0; mt < 4; mt++)
                #pragma unroll
                for (int nq = 0; nq < 2; nq++)
                    st[mt][nq] = __builtin_amdgcn_mfma_f32_16x16x32_bf16(
                        kf[mt], qf[nq][ks], st[mt][nq], 0, 0, 0);
        }
        __builtin_amdgcn_s_setprio(0);

        // P = exp2(S^T), pack 4 keys -> one b64 swizzled LDS write per (nq,mt)
        #pragma unroll
        for (int nq = 0; nq < 2; nq++)
            #pragma unroll
            for (int mt = 0; mt < 4; mt++) {
                u16x4 h;
                #pragma unroll
                for (int r = 0; r < 4; r++) h[r] = f2b_fast(exp2f(st[mt][nq][r]));
                *(u16x4*)&p_s[(nq * 16 + c16) * 64
                              + (((2 * mt + (quad >> 1)) ^ (c16 & 7)) * 8)
                              + (quad & 1) * 4] = h;
            }

        // O^T += V^T P^T ; l += ones . P^T   (p_s wave-private: no barrier)
        __builtin_amdgcn_s_setprio(1);
        #pragma unroll
        for (int ks = 0; ks < 2; ks++) {
            short8 pf[2];
            #pragma unroll
            for (int nq = 0; nq < 2; nq++) {
                int r = nq * 16 + c16;
                pf[nq] = *(const short8*)&p_s[r * 64 + (((ks * 4 + quad) ^ (c16 & 7)) * 8)];
            }
            short8 vf[4];
            #pragma unroll
            for (int mt = 0; mt < 4; mt++) {
                int r = mt * 16 + c16;
                vf[mt] = *(const short8*)&vs_[r * 64 + (((ks * 4 + quad) ^ (r & 7)) * 8)];
            }
            #pragma unroll
            for (int nq = 0; nq < 2; nq++) {
                lacc[nq] = __builtin_amdgcn_mfma_f32_16x16x32_bf16(ones, pf[nq], lacc[nq], 0, 0, 0);
                #pragma unroll
                for (int mt = 0; mt < 4; mt++)
                    oaccT[mt][nq] = __builtin_amdgcn_mfma_f32_16x16x32_bf16(
                        vf[mt], pf[nq], oaccT[mt][nq], 0, 0, 0);
            }
        }
        __builtin_amdgcn_s_setprio(0);

        if (more) {                      // stage next tile into the other buffer
            u16* kd = k_s[cur ^ 1];
            u16* vd = vt_s[cur ^ 1];
            #pragma unroll
            for (int i = 0; i < 2; i++) {
                int r = ar + i * 32;
                *(u16x8*)&kd[r * 64 + scw[i]] = pk[i];
                *(u16x8*)&vd[r * 64 + scw[i]] = pv[i];
            }
        }
        __syncthreads();                 // next buffer ready; this one reusable
    }

    // epilogue: lane c16 owns q-row; 4 contiguous d per (mt) -> 8B stores
    #pragma unroll
    for (int nq = 0; nq < 2; nq++) {
        float rl = 1.f / lacc[nq][0];
        int s = qt * 128 + w * 32 + nq * 16 + c16;
        size_t base = (size_t)(n * S_ + s) * E_ + hh * 64;
        #pragma unroll
        for (int mt = 0; mt < 4; mt++) {
            u16x4 h;
            #pragma unroll
            for (int r = 0; r < 4; r++) h[r] = f2b_fast(oaccT[mt][nq][r] * rl);
            *(u16x4*)&O[base + mt * 16 + quad * 4] = h;
        }
    }
}

// ---------------------------------------------------------------------------
// MFMA GEMM, m97 structure: async global_load_lds (16B) staging into LINEAR
// LDS; ds_read swizzle via pre-swizzled global source (rule #21).
// Chunked XCD swizzle colocates same-A-panel blocks on one XCD's L2.
template <int MT, int NT, bool RELU, bool HASRES, bool OUTF32, bool OUTBF16>
__global__ __launch_bounds__(256, 2) void gemm_mfma(
    const u16* __restrict__ A, const u16* __restrict__ Bt,
    const float* __restrict__ bias, const u16* __restrict__ resid,
    float* __restrict__ outf, u16* __restrict__ outb, int M, int Nc, int K)
{
    constexpr int MFR = MT / 32;
    constexpr int NFR = NT / 32;
    constexpr int AI  = MT / 32;
    constexpr int BI  = NT / 32;
    __shared__ u16 a_s[MT * 64];
    __shared__ u16 b_s[NT * 64];

    int t = threadIdx.x;
    int w = t >> 6, lane = t & 63, quad = lane >> 4, c16 = lane & 15;
    int rw = w >> 1, cw = w & 1;

    int gx = gridDim.x;
    int nwg = gx * (int)gridDim.y;
    int lin = (int)blockIdx.y * gx + (int)blockIdx.x;
    int cpx = nwg >> 3;
    int id2 = (lin & 7) * cpx + (lin >> 3);
    int bx = id2 % gx, by = id2 / gx;

    size_t row0 = (size_t)by * MT;
    size_t col0 = (size_t)bx * NT;

    size_t aoff[AI]; int adst[AI];
    #pragma unroll
    for (int i = 0; i < AI; i++) {
        int p = t + i * 256;
        int r = p >> 3;
        int kc = (p & 7) ^ (r & 7);
        aoff[i] = (row0 + r) * (size_t)K + kc * 8;
        adst[i] = w * 512 + i * 2048;
    }
    size_t boff[BI]; int bdst[BI];
    #pragma unroll
    for (int i = 0; i < BI; i++) {
        int p = t + i * 256;
        int r = p >> 3;
        int kc = (p & 7) ^ (r & 7);
        boff[i] = (col0 + r) * (size_t)K + kc * 8;
        bdst[i] = w * 512 + i * 2048;
    }

    floatx4 acc[MFR][NFR];
    #pragma unroll
    for (int mt = 0; mt < MFR; mt++)
        #pragma unroll
        for (int nt = 0; nt < NFR; nt++) acc[mt][nt] = (floatx4){0.f, 0.f, 0.f, 0.f};

    for (int k0 = 0; k0 < K; k0 += 64) {
        #pragma unroll
        for (int i = 0; i < AI; i++) gload16(A + aoff[i] + k0, a_s + adst[i]);
        #pragma unroll
        for (int i = 0; i < BI; i++) gload16(Bt + boff[i] + k0, b_s + bdst[i]);
        __syncthreads();

        #pragma unroll
        for (int ks = 0; ks < 2; ks++) {
            short8 af[MFR], bfr[NFR];
            #pragma unroll
            for (int mt = 0; mt < MFR; mt++) {
                int r = rw * (MT / 2) + mt * 16 + c16;
                af[mt] = *(const short8*)&a_s[r * 64 + (((ks * 4 + quad) ^ (r & 7)) * 8)];
            }
            #pragma unroll
            for (int nt = 0; nt < NFR; nt++) {
                int r = cw * (NT / 2) + nt * 16 + c16;
                bfr[nt] = *(const short8*)&b_s[r * 64 + (((ks * 4 + quad) ^ (r & 7)) * 8)];
            }
            #pragma unroll
            for (int mt = 0; mt < MFR; mt++)
                #pragma unroll
                for (int nt = 0; nt < NFR; nt++)
                    acc[mt][nt] = __builtin_amdgcn_mfma_f32_16x16x32_bf16(
                        af[mt], bfr[nt], acc[mt][nt], 0, 0, 0);
        }
        __syncthreads();
    }

    #pragma unroll
    for (int nt = 0; nt < NFR; nt++) {
        int col = (int)col0 + cw * (NT / 2) + nt * 16 + c16;
        float bv = bias[col];
        #pragma unroll
        for (int mt = 0; mt < MFR; mt++) {
            size_t rowb = row0 + rw * (MT / 2) + mt * 16 + quad * 4;
            #pragma unroll
            for (int r = 0; r < 4; r++) {
                size_t row = rowb + r;
                float v = acc[mt][nt][r] + bv;
                if constexpr (HASRES) v += b2f(resid[row * Nc + col]);
                if constexpr (RELU) v = fmaxf(v, 0.f);
                if constexpr (OUTF32) outf[row * Nc + col] = v;
                if constexpr (OUTBF16) outb[row * Nc + col] = f2b_fast(v);
            }
        }
    }
}

// ---------------------------------------------------------------------------
// LayerNorm over E=512, one block per row; fp32 in, bf16 out.
// float2-vectorized loads (G13), packed 4B bf16x2 stores.
__global__ __launch_bounds__(256) void layernorm_k(
    const float* __restrict__ in, const float* __restrict__ g,
    const float* __restrict__ bb, u16* __restrict__ outb)
{
    int row = blockIdx.x;
    int t = threadIdx.x;
    const float* x = in + (size_t)row * E_;
    float2 xv = *(const float2*)&x[t * 2];
    float s = xv.x + xv.y;
    #pragma unroll
    for (int off = 32; off; off >>= 1) s += __shfl_down(s, off, 64);
    __shared__ float red[4];
    int wid = t >> 6, lane = t & 63;
    if (lane == 0) red[wid] = s;
    __syncthreads();
    float m = (red[0] + red[1] + red[2] + red[3]) * (1.f / E_);
    float d0 = xv.x - m, d1 = xv.y - m;
    float sq = d0 * d0 + d1 * d1;
    #pragma unroll
    for (int off = 32; off; off >>= 1) sq += __shfl_down(sq, off, 64);
    __syncthreads();
    if (lane == 0) red[wid] = sq;
    __syncthreads();
    float var = (red[0] + red[1] + red[2] + red[3]) * (1.f / E_);
    float rstd = rsqrtf(var + 1e-5f);
    float2 gv = *(const float2*)&g[t * 2];
    float2 bv = *(const float2*)&bb[t * 2];
    unsigned o = (unsigned)f2b_fast(d0 * rstd * gv.x + bv.x)
               | ((unsigned)f2b_fast(d1 * rstd * gv.y + bv.y) << 16);
    *(unsigned*)&outb[(size_t)row * E_ + t * 2] = o;
}

// ---------------------------------------------------------------------------
// MFMA final projection: out[n,o,s] = resb[n*S+s,:] @ Wfint[o,:] + bfin[o]
__global__ __launch_bounds__(256) void final_mfma(
    const u16* __restrict__ hb, const u16* __restrict__ wft,
    const float* __restrict__ bfin, float* __restrict__ outp)
{
    __shared__ u16 a_s[64][72];
    int t = threadIdx.x;
    int w = t >> 6, lane = t & 63, quad = lane >> 4, c16 = lane & 15;
    size_t row0 = (size_t)blockIdx.x * 64;

    floatx4 acc[4];
    #pragma unroll
    for (int nt = 0; nt < 4; nt++) acc[nt] = (floatx4){0.f, 0.f, 0.f, 0.f};

    int ar = t >> 3, acq = (t & 7) * 8;
    u16x8 pa[2];
    #pragma unroll
    for (int i = 0; i < 2; i++)
        pa[i] = *(const u16x8*)&hb[(row0 + ar + i * 32) * E_ + acq];

    for (int k0 = 0; k0 < E_; k0 += 64) {
        #pragma unroll
        for (int i = 0; i < 2; i++)
            *(u16x8*)&a_s[ar + i * 32][acq] = pa[i];
        __syncthreads();
        if (k0 + 64 < E_) {
            #pragma unroll
            for (int i = 0; i < 2; i++)
                pa[i] = *(const u16x8*)&hb[(row0 + ar + i * 32) * E_ + k0 + 64 + acq];
        }
        #pragma unroll
        for (int ks = 0; ks < 2; ks++) {
            short8 af = *(const short8*)&a_s[w * 16 + c16][ks * 32 + quad * 8];
            #pragma unroll
            for (int nt = 0; nt < 4; nt++) {
                short8 bf = *(const short8*)&wft[(nt * 16 + c16) * E_ + k0 + ks * 32 + quad * 8];
                acc[nt] = __builtin_amdgcn_mfma_f32_16x16x32_bf16(af, bf, acc[nt], 0, 0, 0);
            }
        }
        __syncthreads();
    }

    #pragma unroll
    for (int nt = 0; nt < 4; nt++) {
        int o = nt * 16 + c16;
        float bv = bfin[o];
        #pragma unroll
        for (int r = 0; r < 4; r++) {
            size_t row = row0 + w * 16 + quad * 4 + r;    // n*S + s
            int n = (int)(row >> 10), s = (int)(row & 1023);
            outp[((size_t)(n * O_ + o)) * S_ + s] = acc[nt][r] + bv;
        }
    }
}

// ---------------------------------------------------------------------------
extern "C" void kernel_launch(void* const* d_in, const int* in_sizes, int n_in,
                              void* d_out, int out_size, void* d_ws, size_t ws_size,
                              hipStream_t stream)
{
    const float* x       = (const float*)d_in[0];
    const float* W_first = (const float*)d_in[1];
    const float* b_first = (const float*)d_in[2];
    const float* pos_emb = (const float*)d_in[3];
    const float* Wq      = (const float*)d_in[4];
    const float* bq      = (const float*)d_in[5];
    const float* Wk      = (const float*)d_in[6];
    const float* bk      = (const float*)d_in[7];
    const float* Wv      = (const float*)d_in[8];
    const float* bv      = (const float*)d_in[9];
    const float* Wo      = (const float*)d_in[10];
    const float* bo      = (const float*)d_in[11];
    const float* g1      = (const float*)d_in[12];
    const float* be1     = (const float*)d_in[13];
    const float* Wf1     = (const float*)d_in[14];
    const float* bf1     = (const float*)d_in[15];
    const float* Wf2     = (const float*)d_in[16];
    const float* bf2     = (const float*)d_in[17];
    const float* g2      = (const float*)d_in[18];
    const float* be2     = (const float*)d_in[19];
    const float* Wfin    = (const float*)d_in[20];
    const float* bfin    = (const float*)d_in[21];
    float* out = (float*)d_out;

    const size_t M4 = (size_t)N_ * S_ * E_;       // 4,194,304
    float* t1   = (float*)d_ws;                   // fp32 LN input
    u16*   resb = (u16*)(t1 + M4);                // bf16 residual stream (h/hx)
    u16*   qb   = resb + M4;
    u16*   kb   = qb + M4;
    u16*   vt   = kb + M4;
    u16*   ob   = vt + M4;
    u16*   ffb  = qb;                             // alias qb..ob (4*M4 = 32MB)
    u16*   wot  = ob + M4;                        // 6 * 512*512
    u16*   wf1t = wot + (size_t)L_ * E_ * E_;     // 6 * 2048*512 (as [FF][E])
    u16*   wf2t = wf1t + (size_t)L_ * E_ * FF_;   // 6 * 512*2048 (as [E][FF])
    u16*   wqt  = wf2t + (size_t)L_ * FF_ * E_;   // 6 * 64*64
    u16*   wkt  = wqt + (size_t)L_ * HD_ * HD_;
    u16*   wvt  = wkt + (size_t)L_ * HD_ * HD_;
    u16*   wft  = wvt + (size_t)L_ * HD_ * HD_;   // 64*512  (Wfin as [O][E])
    u16*   w1t  = wft + (size_t)O_ * E_;          // 512*64  (W_first as [E][F])

    const int rows = N_ * S_;                     // 8192

    wprep<<<32 + 1536 + 12288 + 32 + 6, 256, 0, stream>>>(
        W_first, Wo, Wf1, Wf2, Wfin, Wq, Wk, Wv,
        w1t, wot, wf1t, wf2t, wft, wqt, wkt, wvt);

    first_mfma<<<dim3(E_ / 128, rows / 128), 256, 0, stream>>>(
        x, w1t, b_first, pos_emb, resb);

    for (int i = 0; i < L_; i++) {
        qkv_mfma<<<512, 256, 0, stream>>>(
            resb, wqt + (size_t)i * HD_ * HD_, wkt + (size_t)i * HD_ * HD_,
            wvt + (size_t)i * HD_ * HD_, bq + i * HD_, bk + i * HD_, bv + i * HD_,
            qb, kb, vt);
        attn_mfma<<<512, 256, 0, stream>>>(qb, kb, vt, ob);
        // t1 = ob @ Wo + bo + resb(h)
        gemm_mfma<128, 64, false, true, true, false><<<dim3(E_ / 64, rows / 128), 256, 0, stream>>>(
            ob, wot + (size_t)i * E_ * E_, bo + i * E_, resb, t1, nullptr, rows, E_, E_);
        layernorm_k<<<rows, 256, 0, stream>>>(t1, g1 + i * E_, be1 + i * E_, resb);
        // ffb = relu(resb(hx) @ Wf1 + bf1)
        gemm_mfma<128, 128, true, false, false, true><<<dim3(FF_ / 128, rows / 128), 256, 0, stream>>>(
            resb, wf1t + (size_t)i * E_ * FF_, bf1 + i * FF_, nullptr, nullptr, ffb,
            rows, FF_, E_);
        // t1 = ffb @ Wf2 + bf2 + resb(hx)
        gemm_mfma<128, 64, false, true, true, false><<<dim3(E_ / 64, rows / 128), 256, 0, stream>>>(
            ffb, wf2t + (size_t)i * FF_ * E_, bf2 + i * E_, resb, t1, nullptr,
            rows, E_, FF_);
        layernorm_k<<<rows, 256, 0, stream>>>(t1, g2 + i * E_, be2 + i * E_, resb);
    }

    final_mfma<<<rows / 64, 256, 0, stream>>>(resb, wft, bfin, out);
}

// Round 7
// 958.406 us; speedup vs baseline: 1.5242x; 1.0343x over previous
//
#include <hip/hip_runtime.h>
#include <hip/hip_bf16.h>
#include <math.h>

// Problem constants
#define N_ 8
#define S_ 1024
#define F_ 64
#define E_ 512
#define H_ 8
#define O_ 64
#define L_ 6
#define HD_ 64
#define FF_ 2048
#define SCALE_ 0.044194173824159216f   // 1/sqrt(E) -- module scales by sqrt(embed_size)
#define LOG2E_ 1.4426950408889634f
#define QSCALE_ (SCALE_ * LOG2E_)      // folded into Q at projection time

typedef unsigned short u16;
typedef __attribute__((ext_vector_type(4))) unsigned short u16x4;
typedef __attribute__((ext_vector_type(8))) unsigned short u16x8;
typedef __attribute__((ext_vector_type(8))) short short8;
typedef __attribute__((ext_vector_type(4))) float floatx4;

__device__ __forceinline__ u16 f2b(float f) {          // RNE (weights, one-time)
    union { float f; unsigned u; } v; v.f = f;
    unsigned u = v.u;
    unsigned r = (u + 0x7FFFu + ((u >> 16) & 1u)) >> 16;
    return (u16)r;
}
__device__ __forceinline__ u16 f2b_fast(float f) {     // round-nearest, 2 ops
    union { float f; unsigned u; } v; v.f = f;
    return (u16)((v.u + 0x8000u) >> 16);
}
__device__ __forceinline__ float b2f(u16 h) {
    union { unsigned u; float f; } v; v.u = ((unsigned)h) << 16;
    return v.f;
}

// async global->LDS, 16B per lane. LDS dest is wave-uniform base + lane*16.
__device__ __forceinline__ void gload16(const u16* g, u16* l) {
    __builtin_amdgcn_global_load_lds(
        (const __attribute__((address_space(1))) void*)g,
        (__attribute__((address_space(3))) void*)l, 16, 0, 0);
}

// ---------------------------------------------------------------------------
// MFMA first projection: h = relu(x^T W + b) + pos -> bf16 residual stream.
__global__ __launch_bounds__(256) void first_mfma(
    const float* __restrict__ x, const u16* __restrict__ wt,
    const float* __restrict__ bf, const float* __restrict__ pe,
    u16* __restrict__ resb)
{
    __shared__ u16 a_s[128][72];
    int t = threadIdx.x;
    int w = t >> 6, lane = t & 63, quad = lane >> 4, c16 = lane & 15;
    int rowhalf = w >> 1, colhalf = w & 1;
    int col0 = blockIdx.x * 128;
    int row0 = blockIdx.y * 128;          // n*S + s0 (never crosses n)
    int n = row0 >> 10, s0 = row0 & 1023;

    const float* xb = x + (size_t)n * F_ * S_ + s0;
    #pragma unroll
    for (int i = 0; i < 8; i++) {
        int pos = (t + i * 256) * 4;      // 8192 elems, f-major
        int f = pos >> 7, sl = pos & 127;
        float4 v = *(const float4*)&xb[(size_t)f * S_ + sl];
        a_s[sl + 0][f] = f2b_fast(v.x);
        a_s[sl + 1][f] = f2b_fast(v.y);
        a_s[sl + 2][f] = f2b_fast(v.z);
        a_s[sl + 3][f] = f2b_fast(v.w);
    }
    __syncthreads();

    floatx4 acc[4][4];
    #pragma unroll
    for (int mt = 0; mt < 4; mt++)
        #pragma unroll
        for (int nt = 0; nt < 4; nt++) acc[mt][nt] = (floatx4){0.f, 0.f, 0.f, 0.f};

    #pragma unroll
    for (int ks = 0; ks < 2; ks++) {
        short8 af[4], bfr[4];
        #pragma unroll
        for (int mt = 0; mt < 4; mt++)
            af[mt] = *(const short8*)&a_s[rowhalf * 64 + mt * 16 + c16][ks * 32 + quad * 8];
        #pragma unroll
        for (int nt = 0; nt < 4; nt++)
            bfr[nt] = *(const short8*)&wt[(size_t)(col0 + colhalf * 64 + nt * 16 + c16) * F_
                                          + ks * 32 + quad * 8];
        #pragma unroll
        for (int mt = 0; mt < 4; mt++)
            #pragma unroll
            for (int nt = 0; nt < 4; nt++)
                acc[mt][nt] = __builtin_amdgcn_mfma_f32_16x16x32_bf16(
                    af[mt], bfr[nt], acc[mt][nt], 0, 0, 0);
    }

    #pragma unroll
    for (int nt = 0; nt < 4; nt++) {
        int col = col0 + colhalf * 64 + nt * 16 + c16;
        float bv = bf[col];
        #pragma unroll
        for (int mt = 0; mt < 4; mt++) {
            #pragma unroll
            for (int r = 0; r < 4; r++) {
                size_t row = (size_t)row0 + rowhalf * 64 + mt * 16 + quad * 4 + r;
                int s = (int)(row & 1023);
                float v = fmaxf(acc[mt][nt][r] + bv, 0.f) + pe[(size_t)s * E_ + col];
                resb[row * E_ + col] = f2b_fast(v);
            }
        }
    }
}

// ---------------------------------------------------------------------------
// ONE-launch weight prep: all cast+transposes + qkv weights, dispatched by
// blockIdx range. Replaces 6 separate launches.
__global__ __launch_bounds__(256) void wprep(
    const float* __restrict__ W_first, const float* __restrict__ Wo,
    const float* __restrict__ Wf1, const float* __restrict__ Wf2,
    const float* __restrict__ Wfin,
    const float* __restrict__ Wq, const float* __restrict__ Wk,
    const float* __restrict__ Wv,
    u16* __restrict__ w1t, u16* __restrict__ wot, u16* __restrict__ wf1t,
    u16* __restrict__ wf2t, u16* __restrict__ wft,
    u16* __restrict__ wqt, u16* __restrict__ wkt, u16* __restrict__ wvt)
{
    int b = blockIdx.x;
    int t = threadIdx.x;
    __shared__ float tile[32][33];
    const float* W; u16* Wt; int K, Nc, bx, by;
    if (b < 32) {                         // W_first: K=64, Nc=512
        W = W_first; Wt = w1t; K = F_; Nc = E_; bx = b & 15; by = b >> 4;
    } else if (b < 32 + 1536) {           // Wo x6: K=512, Nc=512
        int i = b - 32; int z = i >> 8; int r = i & 255;
        W = Wo + (size_t)z * E_ * E_; Wt = wot + (size_t)z * E_ * E_;
        K = E_; Nc = E_; bx = r & 15; by = r >> 4;
    } else if (b < 32 + 1536 + 6144) {    // Wf1 x6: K=512, Nc=2048
        int i = b - (32 + 1536); int z = i >> 10; int r = i & 1023;
        W = Wf1 + (size_t)z * E_ * FF_; Wt = wf1t + (size_t)z * E_ * FF_;
        K = E_; Nc = FF_; bx = r & 63; by = r >> 6;
    } else if (b < 32 + 1536 + 12288) {   // Wf2 x6: K=2048, Nc=512
        int i = b - (32 + 1536 + 6144); int z = i >> 10; int r = i & 1023;
        W = Wf2 + (size_t)z * FF_ * E_; Wt = wf2t + (size_t)z * FF_ * E_;
        K = FF_; Nc = E_; bx = r & 15; by = r >> 4;
    } else if (b < 32 + 1536 + 12288 + 32) { // Wfin: K=512, Nc=64
        int r = b - (32 + 1536 + 12288);
        W = Wfin; Wt = wft; K = E_; Nc = O_; bx = r & 1; by = r >> 1;
    } else {                              // qkv weights: 6 blocks (1/layer)
        int l = b - (32 + 1536 + 12288 + 32);
        size_t off = (size_t)l * HD_ * HD_;
        #pragma unroll
        for (int i = 0; i < 16; i++) {
            int idx = t + i * 256;        // = e*64 + d
            int e = idx >> 6, d = idx & 63;
            wqt[off + idx] = f2b(Wq[off + d * HD_ + e]);
            wkt[off + idx] = f2b(Wk[off + d * HD_ + e]);
            wvt[off + idx] = f2b(Wv[off + d * HD_ + e]);
        }
        return;
    }
    #pragma unroll
    for (int i = 0; i < 4; i++) {
        int q = t + i * 256; int r = q >> 5, c = q & 31;
        tile[r][c] = W[(size_t)(by * 32 + r) * Nc + bx * 32 + c];
    }
    __syncthreads();
    #pragma unroll
    for (int i = 0; i < 4; i++) {
        int q = t + i * 256; int r = q >> 5, c = q & 31;
        Wt[(size_t)(bx * 32 + r) * K + by * 32 + c] = f2b(tile[c][r]);
    }
}

// ---------------------------------------------------------------------------
// MFMA fused qkv; Q pre-scaled by QSCALE_; V written DIRECTLY transposed
// (N,H,D,S) via LDS re-transpose. A-fragments read DIRECT from global
// (rows are 128B, row-contiguous across lanes -> coalesced, L2-served).
__global__ __launch_bounds__(256) void qkv_mfma(
    const u16* __restrict__ hb,
    const u16* __restrict__ wqt, const u16* __restrict__ wkt,
    const u16* __restrict__ wvt,
    const float* __restrict__ bq, const float* __restrict__ bk,
    const float* __restrict__ bvp,
    u16* __restrict__ qo, u16* __restrict__ ko, u16* __restrict__ vt)
{
    __shared__ u16 vt_s[128 * 64];       // only for the V transpose
    int t = threadIdx.x;
    int w = t >> 6, lane = t & 63, quad = lane >> 4, c16 = lane & 15;
    size_t row0 = (size_t)blockIdx.x * 128;

    short8 af[2][2];
    #pragma unroll
    for (int mt = 0; mt < 2; mt++)
        #pragma unroll
        for (int ks = 0; ks < 2; ks++)
            af[mt][ks] = *(const short8*)&hb[(row0 + w * 32 + mt * 16 + c16) * HD_
                                             + ks * 32 + quad * 8];

    // ---- Q (m=0) and K (m=1): normal row-major stores --------------------
    const u16* wts[2] = {wqt, wkt};
    const float* bs[2] = {bq, bk};
    u16* outs[2] = {qo, ko};
    #pragma unroll
    for (int m = 0; m < 2; m++) {
        short8 bfr[4][2];
        #pragma unroll
        for (int nt = 0; nt < 4; nt++)
            #pragma unroll
            for (int ks = 0; ks < 2; ks++)
                bfr[nt][ks] = *(const short8*)&wts[m][(nt * 16 + c16) * HD_ + ks * 32 + quad * 8];
        floatx4 acc[2][4];
        #pragma unroll
        for (int mt = 0; mt < 2; mt++)
            #pragma unroll
            for (int nt = 0; nt < 4; nt++) acc[mt][nt] = (floatx4){0.f, 0.f, 0.f, 0.f};
        #pragma unroll
        for (int ks = 0; ks < 2; ks++)
            #pragma unroll
            for (int mt = 0; mt < 2; mt++)
                #pragma unroll
                for (int nt = 0; nt < 4; nt++)
                    acc[mt][nt] = __builtin_amdgcn_mfma_f32_16x16x32_bf16(
                        af[mt][ks], bfr[nt][ks], acc[mt][nt], 0, 0, 0);
        float osc = (m == 0) ? QSCALE_ : 1.0f;
        #pragma unroll
        for (int nt = 0; nt < 4; nt++) {
            float bv_ = bs[m][nt * 16 + c16];
            #pragma unroll
            for (int mt = 0; mt < 2; mt++)
                #pragma unroll
                for (int r = 0; r < 4; r++)
                    outs[m][(row0 + w * 32 + mt * 16 + quad * 4 + r) * HD_ + nt * 16 + c16] =
                        f2b_fast((acc[mt][nt][r] + bv_) * osc);
        }
    }

    // ---- V (m=2): compute, then transpose via LDS to (N,H,D,S) -----------
    {
        short8 bfr[4][2];
        #pragma unroll
        for (int nt = 0; nt < 4; nt++)
            #pragma unroll
            for (int ks = 0; ks < 2; ks++)
                bfr[nt][ks] = *(const short8*)&wvt[(nt * 16 + c16) * HD_ + ks * 32 + quad * 8];
        floatx4 acc[2][4];
        #pragma unroll
        for (int mt = 0; mt < 2; mt++)
            #pragma unroll
            for (int nt = 0; nt < 4; nt++) acc[mt][nt] = (floatx4){0.f, 0.f, 0.f, 0.f};
        #pragma unroll
        for (int ks = 0; ks < 2; ks++)
            #pragma unroll
            for (int mt = 0; mt < 2; mt++)
                #pragma unroll
                for (int nt = 0; nt < 4; nt++)
                    acc[mt][nt] = __builtin_amdgcn_mfma_f32_16x16x32_bf16(
                        af[mt][ks], bfr[nt][ks], acc[mt][nt], 0, 0, 0);

        #pragma unroll
        for (int nt = 0; nt < 4; nt++) {
            float bv_ = bvp[nt * 16 + c16];
            #pragma unroll
            for (int mt = 0; mt < 2; mt++)
                #pragma unroll
                for (int r = 0; r < 4; r++) {
                    int fr = w * 32 + mt * 16 + quad * 4 + r;   // flat row in block
                    int h = fr & 7, sl = fr >> 3;
                    vt_s[((h * 64 + nt * 16 + c16) * 16) + sl] =
                        f2b_fast(acc[mt][nt][r] + bv_);
                }
        }
        __syncthreads();
        int sflat0 = (int)(row0 >> 3);   // 16-aligned; same n for whole block
        int n = sflat0 >> 10, sbase = sflat0 & 1023;
        #pragma unroll
        for (int i = 0; i < 4; i++) {
            int u = t + i * 256;         // 1024 units of 16B
            int h = u >> 7, rest = u & 127, d = rest >> 1, half = rest & 1;
            *(u16x8*)&vt[((size_t)((n * 8 + h) * 64 + d)) * (size_t)S_ + sbase + half * 8] =
                *(u16x8*)&vt_s[(h * 64 + d) * 16 + half * 8];
        }
    }
}

// ---------------------------------------------------------------------------
// MFMA flash attention: QBLK=128 with 512 threads / 8 waves (16-row q-strips)
// -> 4 waves/SIMD at identical grid+HBM traffic (latency chain hidden by TLP).
// Double-buffered K/V, ONE barrier per k-tile, XOR-swizzled stride-64 LDS,
// setprio, chunked bid swizzle. 48KB LDS, grid 512.
__global__ __launch_bounds__(512, 4) void attn_mfma(
    const u16* __restrict__ Q, const u16* __restrict__ K,
    const u16* __restrict__ Vt, u16* __restrict__ O)
{
    int bid0 = blockIdx.x;               // 512 = N*H*(S/128)
    int bid = (bid0 & 7) * 64 + (bid0 >> 3);    // chunked XCD swizzle
    int qt = bid & 7, hh = (bid >> 3) & 7, n = bid >> 6;
    int t = threadIdx.x;
    int w = t >> 6, lane = t & 63, quad = lane >> 4, c16 = lane & 15;

    __shared__ u16 qp_s[128 * 64];       // Q tile; 8x16-row P strips alias it
    __shared__ u16 k_s[2][64 * 64];      // K rows (key, d), double-buffered
    __shared__ u16 vt_s[2][64 * 64];     // Vt rows (d, key), double-buffered
    u16* p_s = qp_s + w * 16 * 64;       // wave-private 16-row strip

    const size_t qkbase = (size_t)n * S_ * E_ + hh * 64;
    const size_t vtbase = ((size_t)(n * H_ + hh) * 64) * (size_t)S_;

    int ar = t >> 3, act = t & 7;        // 64 rows x 8 chunks = 512 threads
    int acq = act * 8;
    int scw = (act ^ (ar & 7)) * 8;

    // Q staging (128 rows x 8 chunks, 2 iters) + KV tile-0 register load
    #pragma unroll
    for (int i = 0; i < 2; i++) {
        int q = t + i * 512; int r = q >> 3, c = q & 7;
        *(u16x8*)&qp_s[r * 64 + ((c ^ (r & 7)) * 8)] =
            *(const u16x8*)&Q[qkbase + (size_t)(qt * 128 + r) * E_ + c * 8];
    }
    u16x8 pk = *(const u16x8*)&K[qkbase + (size_t)ar * E_ + acq];
    u16x8 pv = *(const u16x8*)&Vt[vtbase + (size_t)ar * S_ + acq];
    __syncthreads();                     // Q visible

    // hoist Q fragments (B-operand of S^T): q row w*16 + c16
    short8 qf[2];
    #pragma unroll
    for (int ks = 0; ks < 2; ks++) {
        int r = w * 16 + c16;
        qf[ks] = *(const short8*)&qp_s[r * 64 + (((ks * 4 + quad) ^ (r & 7)) * 8)];
    }

    // write tile 0 into buffer 0
    *(u16x8*)&k_s[0][ar * 64 + scw] = pk;
    *(u16x8*)&vt_s[0][ar * 64 + scw] = pv;
    __syncthreads();                     // tile 0 visible; all qf hoisted

    const short8 ones = {(short)0x3F80, (short)0x3F80, (short)0x3F80, (short)0x3F80,
                         (short)0x3F80, (short)0x3F80, (short)0x3F80, (short)0x3F80};

    floatx4 oaccT[4];                    // [d-tile]: O^T[d][q]
    floatx4 lacc = (floatx4){0.f, 0.f, 0.f, 0.f};
    #pragma unroll
    for (int mt = 0; mt < 4; mt++) oaccT[mt] = (floatx4){0.f, 0.f, 0.f, 0.f};

    for (int k0 = 0; k0 < S_; k0 += 64) {
        int cur = (k0 >> 6) & 1;
        const u16* ks_ = k_s[cur];
        const u16* vs_ = vt_s[cur];
        bool more = (k0 + 64 < S_);
        if (more) {                      // issue next-tile loads early
            pk = *(const u16x8*)&K[qkbase + (size_t)(k0 + 64 + ar) * E_ + acq];
            pv = *(const u16x8*)&Vt[vtbase + (size_t)ar * S_ + k0 + 64 + acq];
        }

        // S^T = K Q^T : st[mt], lane holds S[q=c16][key=mt*16+quad*4+r]
        floatx4 st[4];
        #pragma unroll
        for (int mt = 0; mt < 4; mt++) st[mt] = (floatx4){0.f, 0.f, 0.f, 0.f};
        __builtin_amdgcn_s_setprio(1);
        #pragma unroll
        for (int ks = 0; ks < 2; ks++) {
            short8 kf[4];
            #pragma unroll
            for (int mt = 0; mt < 4; mt++) {
                int r = mt * 16 + c16;
                kf[mt] = *(const short8*)&ks_[r * 64 + (((ks * 4 + quad) ^ (r & 7)) * 8)];
            }
            #pragma unroll
            for (int mt = 0; mt < 4; mt++)
                st[mt] = __builtin_amdgcn_mfma_f32_16x16x32_bf16(
                    kf[mt], qf[ks], st[mt], 0, 0, 0);
        }
        __builtin_amdgcn_s_setprio(0);

        // P = exp2(S^T), pack 4 keys -> one b64 swizzled LDS write per mt
        #pragma unroll
        for (int mt = 0; mt < 4; mt++) {
            u16x4 h;
            #pragma unroll
            for (int r = 0; r < 4; r++) h[r] = f2b_fast(exp2f(st[mt][r]));
            *(u16x4*)&p_s[c16 * 64 + (((2 * mt + (quad >> 1)) ^ (c16 & 7)) * 8)
                          + (quad & 1) * 4] = h;
        }

        // O^T += V^T P^T ; l += ones . P^T   (p_s wave-private: no barrier)
        __builtin_amdgcn_s_setprio(1);
        #pragma unroll
        for (int ks = 0; ks < 2; ks++) {
            short8 pf = *(const short8*)&p_s[c16 * 64 + (((ks * 4 + quad) ^ (c16 & 7)) * 8)];
            short8 vf[4];
            #pragma unroll
            for (int mt = 0; mt < 4; mt++) {
                int r = mt * 16 + c16;
                vf[mt] = *(const short8*)&vs_[r * 64 + (((ks * 4 + quad) ^ (r & 7)) * 8)];
            }
            lacc = __builtin_amdgcn_mfma_f32_16x16x32_bf16(ones, pf, lacc, 0, 0, 0);
            #pragma unroll
            for (int mt = 0; mt < 4; mt++)
                oaccT[mt] = __builtin_amdgcn_mfma_f32_16x16x32_bf16(
                    vf[mt], pf, oaccT[mt], 0, 0, 0);
        }
        __builtin_amdgcn_s_setprio(0);

        if (more) {                      // stage next tile into the other buffer
            *(u16x8*)&k_s[cur ^ 1][ar * 64 + scw] = pk;
            *(u16x8*)&vt_s[cur ^ 1][ar * 64 + scw] = pv;
        }
        __syncthreads();                 // next buffer ready; this one reusable
    }

    // epilogue: lane c16 owns q-row; 4 contiguous d per (mt) -> 8B stores
    {
        float rl = 1.f / lacc[0];
        int s = qt * 128 + w * 16 + c16;
        size_t base = (size_t)(n * S_ + s) * E_ + hh * 64;
        #pragma unroll
        for (int mt = 0; mt < 4; mt++) {
            u16x4 h;
            #pragma unroll
            for (int r = 0; r < 4; r++) h[r] = f2b_fast(oaccT[mt][r] * rl);
            *(u16x4*)&O[base + mt * 16 + quad * 4] = h;
        }
    }
}

// ---------------------------------------------------------------------------
// MFMA GEMM, m97 structure + single-barrier double-buffered global_load_lds:
// barrier at loop top drains the previous iteration's prefetch (which flew
// under the whole MFMA phase); prefetch issued right after the barrier into
// the other buffer. ds_read swizzle via pre-swizzled global source (rule #21).
// Chunked XCD swizzle colocates same-A-panel blocks on one XCD's L2.
template <int MT, int NT, bool RELU, bool HASRES, bool OUTF32, bool OUTBF16>
__global__ __launch_bounds__(256, 2) void gemm_mfma(
    const u16* __restrict__ A, const u16* __restrict__ Bt,
    const float* __restrict__ bias, const u16* __restrict__ resid,
    float* __restrict__ outf, u16* __restrict__ outb, int M, int Nc, int K)
{
    constexpr int MFR = MT / 32;
    constexpr int NFR = NT / 32;
    constexpr int AI  = MT / 32;
    constexpr int BI  = NT / 32;
    __shared__ u16 a_s[2][MT * 64];
    __shared__ u16 b_s[2][NT * 64];

    int t = threadIdx.x;
    int w = t >> 6, lane = t & 63, quad = lane >> 4, c16 = lane & 15;
    int rw = w >> 1, cw = w & 1;

    int gx = gridDim.x;
    int nwg = gx * (int)gridDim.y;
    int lin = (int)blockIdx.y * gx + (int)blockIdx.x;
    int cpx = nwg >> 3;
    int id2 = (lin & 7) * cpx + (lin >> 3);
    int bx = id2 % gx, by = id2 / gx;

    size_t row0 = (size_t)by * MT;
    size_t col0 = (size_t)bx * NT;

    size_t aoff[AI]; int adst[AI];
    #pragma unroll
    for (int i = 0; i < AI; i++) {
        int p = t + i * 256;
        int r = p >> 3;
        int kc = (p & 7) ^ (r & 7);
        aoff[i] = (row0 + r) * (size_t)K + kc * 8;
        adst[i] = w * 512 + i * 2048;
    }
    size_t boff[BI]; int bdst[BI];
    #pragma unroll
    for (int i = 0; i < BI; i++) {
        int p = t + i * 256;
        int r = p >> 3;
        int kc = (p & 7) ^ (r & 7);
        boff[i] = (col0 + r) * (size_t)K + kc * 8;
        bdst[i] = w * 512 + i * 2048;
    }

    floatx4 acc[MFR][NFR];
    #pragma unroll
    for (int mt = 0; mt < MFR; mt++)
        #pragma unroll
        for (int nt = 0; nt < NFR; nt++) acc[mt][nt] = (floatx4){0.f, 0.f, 0.f, 0.f};

    // prologue: stage tile 0 into buffer 0 (async)
    #pragma unroll
    for (int i = 0; i < AI; i++) gload16(A + aoff[i], &a_s[0][adst[i]]);
    #pragma unroll
    for (int i = 0; i < BI; i++) gload16(Bt + boff[i], &b_s[0][bdst[i]]);

    for (int k0 = 0; k0 < K; k0 += 64) {
        int cur = (k0 >> 6) & 1;
        __syncthreads();               // drains vmcnt: cur tile landed; prev reads done
        if (k0 + 64 < K) {             // prefetch next tile, flies under MFMA
            #pragma unroll
            for (int i = 0; i < AI; i++) gload16(A + aoff[i] + k0 + 64, &a_s[cur ^ 1][adst[i]]);
            #pragma unroll
            for (int i = 0; i < BI; i++) gload16(Bt + boff[i] + k0 + 64, &b_s[cur ^ 1][bdst[i]]);
        }

        #pragma unroll
        for (int ks = 0; ks < 2; ks++) {
            short8 af[MFR], bfr[NFR];
            #pragma unroll
            for (int mt = 0; mt < MFR; mt++) {
                int r = rw * (MT / 2) + mt * 16 + c16;
                af[mt] = *(const short8*)&a_s[cur][r * 64 + (((ks * 4 + quad) ^ (r & 7)) * 8)];
            }
            #pragma unroll
            for (int nt = 0; nt < NFR; nt++) {
                int r = cw * (NT / 2) + nt * 16 + c16;
                bfr[nt] = *(const short8*)&b_s[cur][r * 64 + (((ks * 4 + quad) ^ (r & 7)) * 8)];
            }
            #pragma unroll
            for (int mt = 0; mt < MFR; mt++)
                #pragma unroll
                for (int nt = 0; nt < NFR; nt++)
                    acc[mt][nt] = __builtin_amdgcn_mfma_f32_16x16x32_bf16(
                        af[mt], bfr[nt], acc[mt][nt], 0, 0, 0);
        }
    }

    #pragma unroll
    for (int nt = 0; nt < NFR; nt++) {
        int col = (int)col0 + cw * (NT / 2) + nt * 16 + c16;
        float bv = bias[col];
        #pragma unroll
        for (int mt = 0; mt < MFR; mt++) {
            size_t rowb = row0 + rw * (MT / 2) + mt * 16 + quad * 4;
            #pragma unroll
            for (int r = 0; r < 4; r++) {
                size_t row = rowb + r;
                float v = acc[mt][nt][r] + bv;
                if constexpr (HASRES) v += b2f(resid[row * Nc + col]);
                if constexpr (RELU) v = fmaxf(v, 0.f);
                if constexpr (OUTF32) outf[row * Nc + col] = v;
                if constexpr (OUTBF16) outb[row * Nc + col] = f2b_fast(v);
            }
        }
    }
}

// ---------------------------------------------------------------------------
// LayerNorm over E=512, one block per row; fp32 in, bf16 out.
// float2-vectorized loads (G13), packed 4B bf16x2 stores.
__global__ __launch_bounds__(256) void layernorm_k(
    const float* __restrict__ in, const float* __restrict__ g,
    const float* __restrict__ bb, u16* __restrict__ outb)
{
    int row = blockIdx.x;
    int t = threadIdx.x;
    const float* x = in + (size_t)row * E_;
    float2 xv = *(const float2*)&x[t * 2];
    float s = xv.x + xv.y;
    #pragma unroll
    for (int off = 32; off; off >>= 1) s += __shfl_down(s, off, 64);
    __shared__ float red[4];
    int wid = t >> 6, lane = t & 63;
    if (lane == 0) red[wid] = s;
    __syncthreads();
    float m = (red[0] + red[1] + red[2] + red[3]) * (1.f / E_);
    float d0 = xv.x - m, d1 = xv.y - m;
    float sq = d0 * d0 + d1 * d1;
    #pragma unroll
    for (int off = 32; off; off >>= 1) sq += __shfl_down(sq, off, 64);
    __syncthreads();
    if (lane == 0) red[wid] = sq;
    __syncthreads();
    float var = (red[0] + red[1] + red[2] + red[3]) * (1.f / E_);
    float rstd = rsqrtf(var + 1e-5f);
    float2 gv = *(const float2*)&g[t * 2];
    float2 bv = *(const float2*)&bb[t * 2];
    unsigned o = (unsigned)f2b_fast(d0 * rstd * gv.x + bv.x)
               | ((unsigned)f2b_fast(d1 * rstd * gv.y + bv.y) << 16);
    *(unsigned*)&outb[(size_t)row * E_ + t * 2] = o;
}

// ---------------------------------------------------------------------------
// MFMA final projection: out[n,o,s] = resb[n*S+s,:] @ Wfint[o,:] + bfin[o]
__global__ __launch_bounds__(256) void final_mfma(
    const u16* __restrict__ hb, const u16* __restrict__ wft,
    const float* __restrict__ bfin, float* __restrict__ outp)
{
    __shared__ u16 a_s[64][72];
    int t = threadIdx.x;
    int w = t >> 6, lane = t & 63, quad = lane >> 4, c16 = lane & 15;
    size_t row0 = (size_t)blockIdx.x * 64;

    floatx4 acc[4];
    #pragma unroll
    for (int nt = 0; nt < 4; nt++) acc[nt] = (floatx4){0.f, 0.f, 0.f, 0.f};

    int ar = t >> 3, acq = (t & 7) * 8;
    u16x8 pa[2];
    #pragma unroll
    for (int i = 0; i < 2; i++)
        pa[i] = *(const u16x8*)&hb[(row0 + ar + i * 32) * E_ + acq];

    for (int k0 = 0; k0 < E_; k0 += 64) {
        #pragma unroll
        for (int i = 0; i < 2; i++)
            *(u16x8*)&a_s[ar + i * 32][acq] = pa[i];
        __syncthreads();
        if (k0 + 64 < E_) {
            #pragma unroll
            for (int i = 0; i < 2; i++)
                pa[i] = *(const u16x8*)&hb[(row0 + ar + i * 32) * E_ + k0 + 64 + acq];
        }
        #pragma unroll
        for (int ks = 0; ks < 2; ks++) {
            short8 af = *(const short8*)&a_s[w * 16 + c16][ks * 32 + quad * 8];
            #pragma unroll
            for (int nt = 0; nt < 4; nt++) {
                short8 bf = *(const short8*)&wft[(nt * 16 + c16) * E_ + k0 + ks * 32 + quad * 8];
                acc[nt] = __builtin_amdgcn_mfma_f32_16x16x32_bf16(af, bf, acc[nt], 0, 0, 0);
            }
        }
        __syncthreads();
    }

    #pragma unroll
    for (int nt = 0; nt < 4; nt++) {
        int o = nt * 16 + c16;
        float bv = bfin[o];
        #pragma unroll
        for (int r = 0; r < 4; r++) {
            size_t row = row0 + w * 16 + quad * 4 + r;    // n*S + s
            int n = (int)(row >> 10), s = (int)(row & 1023);
            outp[((size_t)(n * O_ + o)) * S_ + s] = acc[nt][r] + bv;
        }
    }
}

// ---------------------------------------------------------------------------
extern "C" void kernel_launch(void* const* d_in, const int* in_sizes, int n_in,
                              void* d_out, int out_size, void* d_ws, size_t ws_size,
                              hipStream_t stream)
{
    const float* x       = (const float*)d_in[0];
    const float* W_first = (const float*)d_in[1];
    const float* b_first = (const float*)d_in[2];
    const float* pos_emb = (const float*)d_in[3];
    const float* Wq      = (const float*)d_in[4];
    const float* bq      = (const float*)d_in[5];
    const float* Wk      = (const float*)d_in[6];
    const float* bk      = (const float*)d_in[7];
    const float* Wv      = (const float*)d_in[8];
    const float* bv      = (const float*)d_in[9];
    const float* Wo      = (const float*)d_in[10];
    const float* bo      = (const float*)d_in[11];
    const float* g1      = (const float*)d_in[12];
    const float* be1     = (const float*)d_in[13];
    const float* Wf1     = (const float*)d_in[14];
    const float* bf1     = (const float*)d_in[15];
    const float* Wf2     = (const float*)d_in[16];
    const float* bf2     = (const float*)d_in[17];
    const float* g2      = (const float*)d_in[18];
    const float* be2     = (const float*)d_in[19];
    const float* Wfin    = (const float*)d_in[20];
    const float* bfin    = (const float*)d_in[21];
    float* out = (float*)d_out;

    const size_t M4 = (size_t)N_ * S_ * E_;       // 4,194,304
    float* t1   = (float*)d_ws;                   // fp32 LN input
    u16*   resb = (u16*)(t1 + M4);                // bf16 residual stream (h/hx)
    u16*   qb   = resb + M4;
    u16*   kb   = qb + M4;
    u16*   vt   = kb + M4;
    u16*   ob   = vt + M4;
    u16*   ffb  = qb;                             // alias qb..ob (4*M4 = 32MB)
    u16*   wot  = ob + M4;                        // 6 * 512*512
    u16*   wf1t = wot + (size_t)L_ * E_ * E_;     // 6 * 2048*512 (as [FF][E])
    u16*   wf2t = wf1t + (size_t)L_ * E_ * FF_;   // 6 * 512*2048 (as [E][FF])
    u16*   wqt  = wf2t + (size_t)L_ * FF_ * E_;   // 6 * 64*64
    u16*   wkt  = wqt + (size_t)L_ * HD_ * HD_;
    u16*   wvt  = wkt + (size_t)L_ * HD_ * HD_;
    u16*   wft  = wvt + (size_t)L_ * HD_ * HD_;   // 64*512  (Wfin as [O][E])
    u16*   w1t  = wft + (size_t)O_ * E_;          // 512*64  (W_first as [E][F])

    const int rows = N_ * S_;                     // 8192

    wprep<<<32 + 1536 + 12288 + 32 + 6, 256, 0, stream>>>(
        W_first, Wo, Wf1, Wf2, Wfin, Wq, Wk, Wv,
        w1t, wot, wf1t, wf2t, wft, wqt, wkt, wvt);

    first_mfma<<<dim3(E_ / 128, rows / 128), 256, 0, stream>>>(
        x, w1t, b_first, pos_emb, resb);

    for (int i = 0; i < L_; i++) {
        qkv_mfma<<<512, 256, 0, stream>>>(
            resb, wqt + (size_t)i * HD_ * HD_, wkt + (size_t)i * HD_ * HD_,
            wvt + (size_t)i * HD_ * HD_, bq + i * HD_, bk + i * HD_, bv + i * HD_,
            qb, kb, vt);
        attn_mfma<<<512, 512, 0, stream>>>(qb, kb, vt, ob);
        // t1 = ob @ Wo + bo + resb(h)
        gemm_mfma<128, 64, false, true, true, false><<<dim3(E_ / 64, rows / 128), 256, 0, stream>>>(
            ob, wot + (size_t)i * E_ * E_, bo + i * E_, resb, t1, nullptr, rows, E_, E_);
        layernorm_k<<<rows, 256, 0, stream>>>(t1, g1 + i * E_, be1 + i * E_, resb);
        // ffb = relu(resb(hx) @ Wf1 + bf1)
        gemm_mfma<128, 128, true, false, false, true><<<dim3(FF_ / 128, rows / 128), 256, 0, stream>>>(
            resb, wf1t + (size_t)i * E_ * FF_, bf1 + i * FF_, nullptr, nullptr, ffb,
            rows, FF_, E_);
        // t1 = ffb @ Wf2 + bf2 + resb(hx)
        gemm_mfma<128, 64, false, true, true, false><<<dim3(E_ / 64, rows / 128), 256, 0, stream>>>(
            ffb, wf2t + (size_t)i * FF_ * E_, bf2 + i * E_, resb, t1, nullptr,
            rows, E_, FF_);
        layernorm_k<<<rows, 256, 0, stream>>>(t1, g2 + i * E_, be2 + i * E_, resb);
    }

    final_mfma<<<rows / 64, 256, 0, stream>>>(resb, wft, bfin, out);
}

// Round 8
// 958.081 us; speedup vs baseline: 1.5248x; 1.0003x over previous
//
#include <hip/hip_runtime.h>
#include <hip/hip_bf16.h>
#include <math.h>

// Problem constants
#define N_ 8
#define S_ 1024
#define F_ 64
#define E_ 512
#define H_ 8
#define O_ 64
#define L_ 6
#define HD_ 64
#define FF_ 2048
#define SCALE_ 0.044194173824159216f   // 1/sqrt(E) -- module scales by sqrt(embed_size)
#define LOG2E_ 1.4426950408889634f
#define QSCALE_ (SCALE_ * LOG2E_)      // folded into Q at projection time

typedef unsigned short u16;
typedef __attribute__((ext_vector_type(4))) unsigned short u16x4;
typedef __attribute__((ext_vector_type(8))) unsigned short u16x8;
typedef __attribute__((ext_vector_type(8))) short short8;
typedef __attribute__((ext_vector_type(4))) float floatx4;

__device__ __forceinline__ u16 f2b(float f) {          // RNE (weights, one-time)
    union { float f; unsigned u; } v; v.f = f;
    unsigned u = v.u;
    unsigned r = (u + 0x7FFFu + ((u >> 16) & 1u)) >> 16;
    return (u16)r;
}
__device__ __forceinline__ u16 f2b_fast(float f) {     // round-nearest, 2 ops
    union { float f; unsigned u; } v; v.f = f;
    return (u16)((v.u + 0x8000u) >> 16);
}
__device__ __forceinline__ float b2f(u16 h) {
    union { unsigned u; float f; } v; v.u = ((unsigned)h) << 16;
    return v.f;
}

// async global->LDS, 16B per lane. LDS dest is wave-uniform base + lane*16.
__device__ __forceinline__ void gload16(const u16* g, u16* l) {
    __builtin_amdgcn_global_load_lds(
        (const __attribute__((address_space(1))) void*)g,
        (__attribute__((address_space(3))) void*)l, 16, 0, 0);
}

// ---------------------------------------------------------------------------
// MFMA first projection: h = relu(x^T W + b) + pos -> bf16 residual stream.
__global__ __launch_bounds__(256) void first_mfma(
    const float* __restrict__ x, const u16* __restrict__ wt,
    const float* __restrict__ bf, const float* __restrict__ pe,
    u16* __restrict__ resb)
{
    __shared__ u16 a_s[128][72];
    int t = threadIdx.x;
    int w = t >> 6, lane = t & 63, quad = lane >> 4, c16 = lane & 15;
    int rowhalf = w >> 1, colhalf = w & 1;
    int col0 = blockIdx.x * 128;
    int row0 = blockIdx.y * 128;          // n*S + s0 (never crosses n)
    int n = row0 >> 10, s0 = row0 & 1023;

    const float* xb = x + (size_t)n * F_ * S_ + s0;
    #pragma unroll
    for (int i = 0; i < 8; i++) {
        int pos = (t + i * 256) * 4;      // 8192 elems, f-major
        int f = pos >> 7, sl = pos & 127;
        float4 v = *(const float4*)&xb[(size_t)f * S_ + sl];
        a_s[sl + 0][f] = f2b_fast(v.x);
        a_s[sl + 1][f] = f2b_fast(v.y);
        a_s[sl + 2][f] = f2b_fast(v.z);
        a_s[sl + 3][f] = f2b_fast(v.w);
    }
    __syncthreads();

    floatx4 acc[4][4];
    #pragma unroll
    for (int mt = 0; mt < 4; mt++)
        #pragma unroll
        for (int nt = 0; nt < 4; nt++) acc[mt][nt] = (floatx4){0.f, 0.f, 0.f, 0.f};

    #pragma unroll
    for (int ks = 0; ks < 2; ks++) {
        short8 af[4], bfr[4];
        #pragma unroll
        for (int mt = 0; mt < 4; mt++)
            af[mt] = *(const short8*)&a_s[rowhalf * 64 + mt * 16 + c16][ks * 32 + quad * 8];
        #pragma unroll
        for (int nt = 0; nt < 4; nt++)
            bfr[nt] = *(const short8*)&wt[(size_t)(col0 + colhalf * 64 + nt * 16 + c16) * F_
                                          + ks * 32 + quad * 8];
        #pragma unroll
        for (int mt = 0; mt < 4; mt++)
            #pragma unroll
            for (int nt = 0; nt < 4; nt++)
                acc[mt][nt] = __builtin_amdgcn_mfma_f32_16x16x32_bf16(
                    af[mt], bfr[nt], acc[mt][nt], 0, 0, 0);
    }

    #pragma unroll
    for (int nt = 0; nt < 4; nt++) {
        int col = col0 + colhalf * 64 + nt * 16 + c16;
        float bv = bf[col];
        #pragma unroll
        for (int mt = 0; mt < 4; mt++) {
            #pragma unroll
            for (int r = 0; r < 4; r++) {
                size_t row = (size_t)row0 + rowhalf * 64 + mt * 16 + quad * 4 + r;
                int s = (int)(row & 1023);
                float v = fmaxf(acc[mt][nt][r] + bv, 0.f) + pe[(size_t)s * E_ + col];
                resb[row * E_ + col] = f2b_fast(v);
            }
        }
    }
}

// ---------------------------------------------------------------------------
// ONE-launch weight prep: all cast+transposes + qkv weights, dispatched by
// blockIdx range. Replaces 6 separate launches.
__global__ __launch_bounds__(256) void wprep(
    const float* __restrict__ W_first, const float* __restrict__ Wo,
    const float* __restrict__ Wf1, const float* __restrict__ Wf2,
    const float* __restrict__ Wfin,
    const float* __restrict__ Wq, const float* __restrict__ Wk,
    const float* __restrict__ Wv,
    u16* __restrict__ w1t, u16* __restrict__ wot, u16* __restrict__ wf1t,
    u16* __restrict__ wf2t, u16* __restrict__ wft,
    u16* __restrict__ wqt, u16* __restrict__ wkt, u16* __restrict__ wvt)
{
    int b = blockIdx.x;
    int t = threadIdx.x;
    __shared__ float tile[32][33];
    const float* W; u16* Wt; int K, Nc, bx, by;
    if (b < 32) {                         // W_first: K=64, Nc=512
        W = W_first; Wt = w1t; K = F_; Nc = E_; bx = b & 15; by = b >> 4;
    } else if (b < 32 + 1536) {           // Wo x6: K=512, Nc=512
        int i = b - 32; int z = i >> 8; int r = i & 255;
        W = Wo + (size_t)z * E_ * E_; Wt = wot + (size_t)z * E_ * E_;
        K = E_; Nc = E_; bx = r & 15; by = r >> 4;
    } else if (b < 32 + 1536 + 6144) {    // Wf1 x6: K=512, Nc=2048
        int i = b - (32 + 1536); int z = i >> 10; int r = i & 1023;
        W = Wf1 + (size_t)z * E_ * FF_; Wt = wf1t + (size_t)z * E_ * FF_;
        K = E_; Nc = FF_; bx = r & 63; by = r >> 6;
    } else if (b < 32 + 1536 + 12288) {   // Wf2 x6: K=2048, Nc=512
        int i = b - (32 + 1536 + 6144); int z = i >> 10; int r = i & 1023;
        W = Wf2 + (size_t)z * FF_ * E_; Wt = wf2t + (size_t)z * FF_ * E_;
        K = FF_; Nc = E_; bx = r & 15; by = r >> 4;
    } else if (b < 32 + 1536 + 12288 + 32) { // Wfin: K=512, Nc=64
        int r = b - (32 + 1536 + 12288);
        W = Wfin; Wt = wft; K = E_; Nc = O_; bx = r & 1; by = r >> 1;
    } else {                              // qkv weights: 6 blocks (1/layer)
        int l = b - (32 + 1536 + 12288 + 32);
        size_t off = (size_t)l * HD_ * HD_;
        #pragma unroll
        for (int i = 0; i < 16; i++) {
            int idx = t + i * 256;        // = e*64 + d
            int e = idx >> 6, d = idx & 63;
            wqt[off + idx] = f2b(Wq[off + d * HD_ + e]);
            wkt[off + idx] = f2b(Wk[off + d * HD_ + e]);
            wvt[off + idx] = f2b(Wv[off + d * HD_ + e]);
        }
        return;
    }
    #pragma unroll
    for (int i = 0; i < 4; i++) {
        int q = t + i * 256; int r = q >> 5, c = q & 31;
        tile[r][c] = W[(size_t)(by * 32 + r) * Nc + bx * 32 + c];
    }
    __syncthreads();
    #pragma unroll
    for (int i = 0; i < 4; i++) {
        int q = t + i * 256; int r = q >> 5, c = q & 31;
        Wt[(size_t)(bx * 32 + r) * K + by * 32 + c] = f2b(tile[c][r]);
    }
}

// ---------------------------------------------------------------------------
// MFMA fused qkv; Q pre-scaled by QSCALE_; V written DIRECTLY transposed
// (N,H,D,S) via LDS re-transpose. A-fragments read DIRECT from global
// (rows are 128B, row-contiguous across lanes -> coalesced, L2-served).
__global__ __launch_bounds__(256) void qkv_mfma(
    const u16* __restrict__ hb,
    const u16* __restrict__ wqt, const u16* __restrict__ wkt,
    const u16* __restrict__ wvt,
    const float* __restrict__ bq, const float* __restrict__ bk,
    const float* __restrict__ bvp,
    u16* __restrict__ qo, u16* __restrict__ ko, u16* __restrict__ vt)
{
    __shared__ u16 vt_s[128 * 64];       // only for the V transpose
    int t = threadIdx.x;
    int w = t >> 6, lane = t & 63, quad = lane >> 4, c16 = lane & 15;
    size_t row0 = (size_t)blockIdx.x * 128;

    short8 af[2][2];
    #pragma unroll
    for (int mt = 0; mt < 2; mt++)
        #pragma unroll
        for (int ks = 0; ks < 2; ks++)
            af[mt][ks] = *(const short8*)&hb[(row0 + w * 32 + mt * 16 + c16) * HD_
                                             + ks * 32 + quad * 8];

    // ---- Q (m=0) and K (m=1): normal row-major stores --------------------
    const u16* wts[2] = {wqt, wkt};
    const float* bs[2] = {bq, bk};
    u16* outs[2] = {qo, ko};
    #pragma unroll
    for (int m = 0; m < 2; m++) {
        short8 bfr[4][2];
        #pragma unroll
        for (int nt = 0; nt < 4; nt++)
            #pragma unroll
            for (int ks = 0; ks < 2; ks++)
                bfr[nt][ks] = *(const short8*)&wts[m][(nt * 16 + c16) * HD_ + ks * 32 + quad * 8];
        floatx4 acc[2][4];
        #pragma unroll
        for (int mt = 0; mt < 2; mt++)
            #pragma unroll
            for (int nt = 0; nt < 4; nt++) acc[mt][nt] = (floatx4){0.f, 0.f, 0.f, 0.f};
        #pragma unroll
        for (int ks = 0; ks < 2; ks++)
            #pragma unroll
            for (int mt = 0; mt < 2; mt++)
                #pragma unroll
                for (int nt = 0; nt < 4; nt++)
                    acc[mt][nt] = __builtin_amdgcn_mfma_f32_16x16x32_bf16(
                        af[mt][ks], bfr[nt][ks], acc[mt][nt], 0, 0, 0);
        float osc = (m == 0) ? QSCALE_ : 1.0f;
        #pragma unroll
        for (int nt = 0; nt < 4; nt++) {
            float bv_ = bs[m][nt * 16 + c16];
            #pragma unroll
            for (int mt = 0; mt < 2; mt++)
                #pragma unroll
                for (int r = 0; r < 4; r++)
                    outs[m][(row0 + w * 32 + mt * 16 + quad * 4 + r) * HD_ + nt * 16 + c16] =
                        f2b_fast((acc[mt][nt][r] + bv_) * osc);
        }
    }

    // ---- V (m=2): compute, then transpose via LDS to (N,H,D,S) -----------
    {
        short8 bfr[4][2];
        #pragma unroll
        for (int nt = 0; nt < 4; nt++)
            #pragma unroll
            for (int ks = 0; ks < 2; ks++)
                bfr[nt][ks] = *(const short8*)&wvt[(nt * 16 + c16) * HD_ + ks * 32 + quad * 8];
        floatx4 acc[2][4];
        #pragma unroll
        for (int mt = 0; mt < 2; mt++)
            #pragma unroll
            for (int nt = 0; nt < 4; nt++) acc[mt][nt] = (floatx4){0.f, 0.f, 0.f, 0.f};
        #pragma unroll
        for (int ks = 0; ks < 2; ks++)
            #pragma unroll
            for (int mt = 0; mt < 2; mt++)
                #pragma unroll
                for (int nt = 0; nt < 4; nt++)
                    acc[mt][nt] = __builtin_amdgcn_mfma_f32_16x16x32_bf16(
                        af[mt][ks], bfr[nt][ks], acc[mt][nt], 0, 0, 0);

        #pragma unroll
        for (int nt = 0; nt < 4; nt++) {
            float bv_ = bvp[nt * 16 + c16];
            #pragma unroll
            for (int mt = 0; mt < 2; mt++)
                #pragma unroll
                for (int r = 0; r < 4; r++) {
                    int fr = w * 32 + mt * 16 + quad * 4 + r;   // flat row in block
                    int h = fr & 7, sl = fr >> 3;
                    vt_s[((h * 64 + nt * 16 + c16) * 16) + sl] =
                        f2b_fast(acc[mt][nt][r] + bv_);
                }
        }
        __syncthreads();
        int sflat0 = (int)(row0 >> 3);   // 16-aligned; same n for whole block
        int n = sflat0 >> 10, sbase = sflat0 & 1023;
        #pragma unroll
        for (int i = 0; i < 4; i++) {
            int u = t + i * 256;         // 1024 units of 16B
            int h = u >> 7, rest = u & 127, d = rest >> 1, half = rest & 1;
            *(u16x8*)&vt[((size_t)((n * 8 + h) * 64 + d)) * (size_t)S_ + sbase + half * 8] =
                *(u16x8*)&vt_s[(h * 64 + d) * 16 + half * 8];
        }
    }
}

// ---------------------------------------------------------------------------
// MFMA flash attention: QBLK=128 with 512 threads / 8 waves (16-row q-strips)
// -> 4 waves/SIMD at identical grid+HBM traffic (latency chain hidden by TLP).
// Double-buffered K/V, ONE barrier per k-tile, XOR-swizzled stride-64 LDS,
// setprio, chunked bid swizzle. 48KB LDS, grid 512.
__global__ __launch_bounds__(512, 4) void attn_mfma(
    const u16* __restrict__ Q, const u16* __restrict__ K,
    const u16* __restrict__ Vt, u16* __restrict__ O)
{
    int bid0 = blockIdx.x;               // 512 = N*H*(S/128)
    int bid = (bid0 & 7) * 64 + (bid0 >> 3);    // chunked XCD swizzle
    int qt = bid & 7, hh = (bid >> 3) & 7, n = bid >> 6;
    int t = threadIdx.x;
    int w = t >> 6, lane = t & 63, quad = lane >> 4, c16 = lane & 15;

    __shared__ u16 qp_s[128 * 64];       // Q tile; 8x16-row P strips alias it
    __shared__ u16 k_s[2][64 * 64];      // K rows (key, d), double-buffered
    __shared__ u16 vt_s[2][64 * 64];     // Vt rows (d, key), double-buffered
    u16* p_s = qp_s + w * 16 * 64;       // wave-private 16-row strip

    const size_t qkbase = (size_t)n * S_ * E_ + hh * 64;
    const size_t vtbase = ((size_t)(n * H_ + hh) * 64) * (size_t)S_;

    int ar = t >> 3, act = t & 7;        // 64 rows x 8 chunks = 512 threads
    int acq = act * 8;
    int scw = (act ^ (ar & 7)) * 8;

    // Q staging (128 rows x 8 chunks, 2 iters) + KV tile-0 register load
    #pragma unroll
    for (int i = 0; i < 2; i++) {
        int q = t + i * 512; int r = q >> 3, c = q & 7;
        *(u16x8*)&qp_s[r * 64 + ((c ^ (r & 7)) * 8)] =
            *(const u16x8*)&Q[qkbase + (size_t)(qt * 128 + r) * E_ + c * 8];
    }
    u16x8 pk = *(const u16x8*)&K[qkbase + (size_t)ar * E_ + acq];
    u16x8 pv = *(const u16x8*)&Vt[vtbase + (size_t)ar * S_ + acq];
    __syncthreads();                     // Q visible

    // hoist Q fragments (B-operand of S^T): q row w*16 + c16
    short8 qf[2];
    #pragma unroll
    for (int ks = 0; ks < 2; ks++) {
        int r = w * 16 + c16;
        qf[ks] = *(const short8*)&qp_s[r * 64 + (((ks * 4 + quad) ^ (r & 7)) * 8)];
    }

    // write tile 0 into buffer 0
    *(u16x8*)&k_s[0][ar * 64 + scw] = pk;
    *(u16x8*)&vt_s[0][ar * 64 + scw] = pv;
    __syncthreads();                     // tile 0 visible; all qf hoisted

    const short8 ones = {(short)0x3F80, (short)0x3F80, (short)0x3F80, (short)0x3F80,
                         (short)0x3F80, (short)0x3F80, (short)0x3F80, (short)0x3F80};

    floatx4 oaccT[4];                    // [d-tile]: O^T[d][q]
    floatx4 lacc = (floatx4){0.f, 0.f, 0.f, 0.f};
    #pragma unroll
    for (int mt = 0; mt < 4; mt++) oaccT[mt] = (floatx4){0.f, 0.f, 0.f, 0.f};

    for (int k0 = 0; k0 < S_; k0 += 64) {
        int cur = (k0 >> 6) & 1;
        const u16* ks_ = k_s[cur];
        const u16* vs_ = vt_s[cur];
        bool more = (k0 + 64 < S_);
        if (more) {                      // issue next-tile loads early
            pk = *(const u16x8*)&K[qkbase + (size_t)(k0 + 64 + ar) * E_ + acq];
            pv = *(const u16x8*)&Vt[vtbase + (size_t)ar * S_ + k0 + 64 + acq];
        }

        // S^T = K Q^T : st[mt], lane holds S[q=c16][key=mt*16+quad*4+r]
        floatx4 st[4];
        #pragma unroll
        for (int mt = 0; mt < 4; mt++) st[mt] = (floatx4){0.f, 0.f, 0.f, 0.f};
        __builtin_amdgcn_s_setprio(1);
        #pragma unroll
        for (int ks = 0; ks < 2; ks++) {
            short8 kf[4];
            #pragma unroll
            for (int mt = 0; mt < 4; mt++) {
                int r = mt * 16 + c16;
                kf[mt] = *(const short8*)&ks_[r * 64 + (((ks * 4 + quad) ^ (r & 7)) * 8)];
            }
            #pragma unroll
            for (int mt = 0; mt < 4; mt++)
                st[mt] = __builtin_amdgcn_mfma_f32_16x16x32_bf16(
                    kf[mt], qf[ks], st[mt], 0, 0, 0);
        }
        __builtin_amdgcn_s_setprio(0);

        // P = exp2(S^T), pack 4 keys -> one b64 swizzled LDS write per mt
        #pragma unroll
        for (int mt = 0; mt < 4; mt++) {
            u16x4 h;
            #pragma unroll
            for (int r = 0; r < 4; r++) h[r] = f2b_fast(exp2f(st[mt][r]));
            *(u16x4*)&p_s[c16 * 64 + (((2 * mt + (quad >> 1)) ^ (c16 & 7)) * 8)
                          + (quad & 1) * 4] = h;
        }

        // O^T += V^T P^T ; l += ones . P^T   (p_s wave-private: no barrier)
        __builtin_amdgcn_s_setprio(1);
        #pragma unroll
        for (int ks = 0; ks < 2; ks++) {
            short8 pf = *(const short8*)&p_s[c16 * 64 + (((ks * 4 + quad) ^ (c16 & 7)) * 8)];
            short8 vf[4];
            #pragma unroll
            for (int mt = 0; mt < 4; mt++) {
                int r = mt * 16 + c16;
                vf[mt] = *(const short8*)&vs_[r * 64 + (((ks * 4 + quad) ^ (r & 7)) * 8)];
            }
            lacc = __builtin_amdgcn_mfma_f32_16x16x32_bf16(ones, pf, lacc, 0, 0, 0);
            #pragma unroll
            for (int mt = 0; mt < 4; mt++)
                oaccT[mt] = __builtin_amdgcn_mfma_f32_16x16x32_bf16(
                    vf[mt], pf, oaccT[mt], 0, 0, 0);
        }
        __builtin_amdgcn_s_setprio(0);

        if (more) {                      // stage next tile into the other buffer
            *(u16x8*)&k_s[cur ^ 1][ar * 64 + scw] = pk;
            *(u16x8*)&vt_s[cur ^ 1][ar * 64 + scw] = pv;
        }
        __syncthreads();                 // next buffer ready; this one reusable
    }

    // epilogue: lane c16 owns q-row; 4 contiguous d per (mt) -> 8B stores
    {
        float rl = 1.f / lacc[0];
        int s = qt * 128 + w * 16 + c16;
        size_t base = (size_t)(n * S_ + s) * E_ + hh * 64;
        #pragma unroll
        for (int mt = 0; mt < 4; mt++) {
            u16x4 h;
            #pragma unroll
            for (int r = 0; r < 4; r++) h[r] = f2b_fast(oaccT[mt][r] * rl);
            *(u16x4*)&O[base + mt * 16 + quad * 4] = h;
        }
    }
}

// ---------------------------------------------------------------------------
// MFMA GEMM. PIPE3=true (128x64 only): 3-buffer 2-deep global_load_lds
// pipeline with COUNTED vmcnt (T4: never drain to 0 in-loop). Per iter:
// s_waitcnt vmcnt(6) [tile i landed; 6 = loads of tile i+1 still in flight]
// -> raw s_barrier -> sched_barrier(0) [pin ds_reads below: other waves'
// gloads land only at THEIR wait] -> issue tile i+2 -> compute tile i.
// Buffer (i+2)%3 was last read at compute(i-1), ordered by barrier(i).
// PIPE3=false: round-7 2-buffer __syncthreads path (Wf1, 128x128).
// ds_read swizzle via pre-swizzled global source (rule #21); chunked XCD
// swizzle colocates same-A-panel blocks on one XCD's L2.
template <int MT, int NT, bool PIPE3, bool RELU, bool HASRES, bool OUTF32, bool OUTBF16>
__global__ __launch_bounds__(256, 2) void gemm_mfma(
    const u16* __restrict__ A, const u16* __restrict__ Bt,
    const float* __restrict__ bias, const u16* __restrict__ resid,
    float* __restrict__ outf, u16* __restrict__ outb, int M, int Nc, int K)
{
    constexpr int MFR = MT / 32;
    constexpr int NFR = NT / 32;
    constexpr int AI  = MT / 32;
    constexpr int BI  = NT / 32;
    constexpr int NBUF = PIPE3 ? 3 : 2;
    static_assert(!PIPE3 || (AI + BI == 6), "vmcnt literal assumes 6 loads/tile");
    __shared__ u16 a_s[NBUF][MT * 64];
    __shared__ u16 b_s[NBUF][NT * 64];

    int t = threadIdx.x;
    int w = t >> 6, lane = t & 63, quad = lane >> 4, c16 = lane & 15;
    int rw = w >> 1, cw = w & 1;

    int gx = gridDim.x;
    int nwg = gx * (int)gridDim.y;
    int lin = (int)blockIdx.y * gx + (int)blockIdx.x;
    int cpx = nwg >> 3;
    int id2 = (lin & 7) * cpx + (lin >> 3);
    int bx = id2 % gx, by = id2 / gx;

    size_t row0 = (size_t)by * MT;
    size_t col0 = (size_t)bx * NT;

    size_t aoff[AI]; int adst[AI];
    #pragma unroll
    for (int i = 0; i < AI; i++) {
        int p = t + i * 256;
        int r = p >> 3;
        int kc = (p & 7) ^ (r & 7);
        aoff[i] = (row0 + r) * (size_t)K + kc * 8;
        adst[i] = w * 512 + i * 2048;
    }
    size_t boff[BI]; int bdst[BI];
    #pragma unroll
    for (int i = 0; i < BI; i++) {
        int p = t + i * 256;
        int r = p >> 3;
        int kc = (p & 7) ^ (r & 7);
        boff[i] = (col0 + r) * (size_t)K + kc * 8;
        bdst[i] = w * 512 + i * 2048;
    }

    floatx4 acc[MFR][NFR];
    #pragma unroll
    for (int mt = 0; mt < MFR; mt++)
        #pragma unroll
        for (int nt = 0; nt < NFR; nt++) acc[mt][nt] = (floatx4){0.f, 0.f, 0.f, 0.f};

    if constexpr (PIPE3) {
        int nt_ = K >> 6;                // K-tiles (>= 8 for all our shapes)
        // prologue: stage tiles 0,1 (12 loads in flight)
        #pragma unroll
        for (int i = 0; i < AI; i++) gload16(A + aoff[i], &a_s[0][adst[i]]);
        #pragma unroll
        for (int i = 0; i < BI; i++) gload16(Bt + boff[i], &b_s[0][bdst[i]]);
        #pragma unroll
        for (int i = 0; i < AI; i++) gload16(A + aoff[i] + 64, &a_s[1][adst[i]]);
        #pragma unroll
        for (int i = 0; i < BI; i++) gload16(Bt + boff[i] + 64, &b_s[1][bdst[i]]);

        int cb = 0, nb = 2;              // compute buf, next-stage buf
        for (int it = 0; it < nt_; ++it) {
            if (it + 1 < nt_) {
                asm volatile("s_waitcnt vmcnt(6)" ::: "memory");
            } else {
                asm volatile("s_waitcnt vmcnt(0)" ::: "memory");
            }
            __builtin_amdgcn_s_barrier();
            __builtin_amdgcn_sched_barrier(0);

            if (it + 2 < nt_) {          // stage tile it+2 into nb
                int k2 = (it + 2) * 64;
                #pragma unroll
                for (int i = 0; i < AI; i++) gload16(A + aoff[i] + k2, &a_s[nb][adst[i]]);
                #pragma unroll
                for (int i = 0; i < BI; i++) gload16(Bt + boff[i] + k2, &b_s[nb][bdst[i]]);
            }

            const u16* ap = a_s[cb];
            const u16* bp = b_s[cb];
            #pragma unroll
            for (int ks = 0; ks < 2; ks++) {
                short8 af[MFR], bfr[NFR];
                #pragma unroll
                for (int mt = 0; mt < MFR; mt++) {
                    int r = rw * (MT / 2) + mt * 16 + c16;
                    af[mt] = *(const short8*)&ap[r * 64 + (((ks * 4 + quad) ^ (r & 7)) * 8)];
                }
                #pragma unroll
                for (int nt = 0; nt < NFR; nt++) {
                    int r = cw * (NT / 2) + nt * 16 + c16;
                    bfr[nt] = *(const short8*)&bp[r * 64 + (((ks * 4 + quad) ^ (r & 7)) * 8)];
                }
                #pragma unroll
                for (int mt = 0; mt < MFR; mt++)
                    #pragma unroll
                    for (int nt = 0; nt < NFR; nt++)
                        acc[mt][nt] = __builtin_amdgcn_mfma_f32_16x16x32_bf16(
                            af[mt], bfr[nt], acc[mt][nt], 0, 0, 0);
            }
            cb = (cb + 1) % 3; nb = (nb + 1) % 3;
        }
    } else {
        // prologue: stage tile 0 into buffer 0 (async)
        #pragma unroll
        for (int i = 0; i < AI; i++) gload16(A + aoff[i], &a_s[0][adst[i]]);
        #pragma unroll
        for (int i = 0; i < BI; i++) gload16(Bt + boff[i], &b_s[0][bdst[i]]);

        for (int k0 = 0; k0 < K; k0 += 64) {
            int cur = (k0 >> 6) & 1;
            __syncthreads();             // drains vmcnt: cur tile landed; prev reads done
            if (k0 + 64 < K) {           // prefetch next tile, flies under MFMA
                #pragma unroll
                for (int i = 0; i < AI; i++) gload16(A + aoff[i] + k0 + 64, &a_s[cur ^ 1][adst[i]]);
                #pragma unroll
                for (int i = 0; i < BI; i++) gload16(Bt + boff[i] + k0 + 64, &b_s[cur ^ 1][bdst[i]]);
            }

            #pragma unroll
            for (int ks = 0; ks < 2; ks++) {
                short8 af[MFR], bfr[NFR];
                #pragma unroll
                for (int mt = 0; mt < MFR; mt++) {
                    int r = rw * (MT / 2) + mt * 16 + c16;
                    af[mt] = *(const short8*)&a_s[cur][r * 64 + (((ks * 4 + quad) ^ (r & 7)) * 8)];
                }
                #pragma unroll
                for (int nt = 0; nt < NFR; nt++) {
                    int r = cw * (NT / 2) + nt * 16 + c16;
                    bfr[nt] = *(const short8*)&b_s[cur][r * 64 + (((ks * 4 + quad) ^ (r & 7)) * 8)];
                }
                #pragma unroll
                for (int mt = 0; mt < MFR; mt++)
                    #pragma unroll
                    for (int nt = 0; nt < NFR; nt++)
                        acc[mt][nt] = __builtin_amdgcn_mfma_f32_16x16x32_bf16(
                            af[mt], bfr[nt], acc[mt][nt], 0, 0, 0);
            }
        }
    }

    #pragma unroll
    for (int nt = 0; nt < NFR; nt++) {
        int col = (int)col0 + cw * (NT / 2) + nt * 16 + c16;
        float bv = bias[col];
        #pragma unroll
        for (int mt = 0; mt < MFR; mt++) {
            size_t rowb = row0 + rw * (MT / 2) + mt * 16 + quad * 4;
            #pragma unroll
            for (int r = 0; r < 4; r++) {
                size_t row = rowb + r;
                float v = acc[mt][nt][r] + bv;
                if constexpr (HASRES) v += b2f(resid[row * Nc + col]);
                if constexpr (RELU) v = fmaxf(v, 0.f);
                if constexpr (OUTF32) outf[row * Nc + col] = v;
                if constexpr (OUTBF16) outb[row * Nc + col] = f2b_fast(v);
            }
        }
    }
}

// ---------------------------------------------------------------------------
// LayerNorm over E=512, one block per row; fp32 in, bf16 out.
// float2-vectorized loads (G13), packed 4B bf16x2 stores.
__global__ __launch_bounds__(256) void layernorm_k(
    const float* __restrict__ in, const float* __restrict__ g,
    const float* __restrict__ bb, u16* __restrict__ outb)
{
    int row = blockIdx.x;
    int t = threadIdx.x;
    const float* x = in + (size_t)row * E_;
    float2 xv = *(const float2*)&x[t * 2];
    float s = xv.x + xv.y;
    #pragma unroll
    for (int off = 32; off; off >>= 1) s += __shfl_down(s, off, 64);
    __shared__ float red[4];
    int wid = t >> 6, lane = t & 63;
    if (lane == 0) red[wid] = s;
    __syncthreads();
    float m = (red[0] + red[1] + red[2] + red[3]) * (1.f / E_);
    float d0 = xv.x - m, d1 = xv.y - m;
    float sq = d0 * d0 + d1 * d1;
    #pragma unroll
    for (int off = 32; off; off >>= 1) sq += __shfl_down(sq, off, 64);
    __syncthreads();
    if (lane == 0) red[wid] = sq;
    __syncthreads();
    float var = (red[0] + red[1] + red[2] + red[3]) * (1.f / E_);
    float rstd = rsqrtf(var + 1e-5f);
    float2 gv = *(const float2*)&g[t * 2];
    float2 bv = *(const float2*)&bb[t * 2];
    unsigned o = (unsigned)f2b_fast(d0 * rstd * gv.x + bv.x)
               | ((unsigned)f2b_fast(d1 * rstd * gv.y + bv.y) << 16);
    *(unsigned*)&outb[(size_t)row * E_ + t * 2] = o;
}

// ---------------------------------------------------------------------------
// MFMA final projection: out[n,o,s] = resb[n*S+s,:] @ Wfint[o,:] + bfin[o]
__global__ __launch_bounds__(256) void final_mfma(
    const u16* __restrict__ hb, const u16* __restrict__ wft,
    const float* __restrict__ bfin, float* __restrict__ outp)
{
    __shared__ u16 a_s[64][72];
    int t = threadIdx.x;
    int w = t >> 6, lane = t & 63, quad = lane >> 4, c16 = lane & 15;
    size_t row0 = (size_t)blockIdx.x * 64;

    floatx4 acc[4];
    #pragma unroll
    for (int nt = 0; nt < 4; nt++) acc[nt] = (floatx4){0.f, 0.f, 0.f, 0.f};

    int ar = t >> 3, acq = (t & 7) * 8;
    u16x8 pa[2];
    #pragma unroll
    for (int i = 0; i < 2; i++)
        pa[i] = *(const u16x8*)&hb[(row0 + ar + i * 32) * E_ + acq];

    for (int k0 = 0; k0 < E_; k0 += 64) {
        #pragma unroll
        for (int i = 0; i < 2; i++)
            *(u16x8*)&a_s[ar + i * 32][acq] = pa[i];
        __syncthreads();
        if (k0 + 64 < E_) {
            #pragma unroll
            for (int i = 0; i < 2; i++)
                pa[i] = *(const u16x8*)&hb[(row0 + ar + i * 32) * E_ + k0 + 64 + acq];
        }
        #pragma unroll
        for (int ks = 0; ks < 2; ks++) {
            short8 af = *(const short8*)&a_s[w * 16 + c16][ks * 32 + quad * 8];
            #pragma unroll
            for (int nt = 0; nt < 4; nt++) {
                short8 bf = *(const short8*)&wft[(nt * 16 + c16) * E_ + k0 + ks * 32 + quad * 8];
                acc[nt] = __builtin_amdgcn_mfma_f32_16x16x32_bf16(af, bf, acc[nt], 0, 0, 0);
            }
        }
        __syncthreads();
    }

    #pragma unroll
    for (int nt = 0; nt < 4; nt++) {
        int o = nt * 16 + c16;
        float bv = bfin[o];
        #pragma unroll
        for (int r = 0; r < 4; r++) {
            size_t row = row0 + w * 16 + quad * 4 + r;    // n*S + s
            int n = (int)(row >> 10), s = (int)(row & 1023);
            outp[((size_t)(n * O_ + o)) * S_ + s] = acc[nt][r] + bv;
        }
    }
}

// ---------------------------------------------------------------------------
extern "C" void kernel_launch(void* const* d_in, const int* in_sizes, int n_in,
                              void* d_out, int out_size, void* d_ws, size_t ws_size,
                              hipStream_t stream)
{
    const float* x       = (const float*)d_in[0];
    const float* W_first = (const float*)d_in[1];
    const float* b_first = (const float*)d_in[2];
    const float* pos_emb = (const float*)d_in[3];
    const float* Wq      = (const float*)d_in[4];
    const float* bq      = (const float*)d_in[5];
    const float* Wk      = (const float*)d_in[6];
    const float* bk      = (const float*)d_in[7];
    const float* Wv      = (const float*)d_in[8];
    const float* bv      = (const float*)d_in[9];
    const float* Wo      = (const float*)d_in[10];
    const float* bo      = (const float*)d_in[11];
    const float* g1      = (const float*)d_in[12];
    const float* be1     = (const float*)d_in[13];
    const float* Wf1     = (const float*)d_in[14];
    const float* bf1     = (const float*)d_in[15];
    const float* Wf2     = (const float*)d_in[16];
    const float* bf2     = (const float*)d_in[17];
    const float* g2      = (const float*)d_in[18];
    const float* be2     = (const float*)d_in[19];
    const float* Wfin    = (const float*)d_in[20];
    const float* bfin    = (const float*)d_in[21];
    float* out = (float*)d_out;

    const size_t M4 = (size_t)N_ * S_ * E_;       // 4,194,304
    float* t1   = (float*)d_ws;                   // fp32 LN input
    u16*   resb = (u16*)(t1 + M4);                // bf16 residual stream (h/hx)
    u16*   qb   = resb + M4;
    u16*   kb   = qb + M4;
    u16*   vt   = kb + M4;
    u16*   ob   = vt + M4;
    u16*   ffb  = qb;                             // alias qb..ob (4*M4 = 32MB)
    u16*   wot  = ob + M4;                        // 6 * 512*512
    u16*   wf1t = wot + (size_t)L_ * E_ * E_;     // 6 * 2048*512 (as [FF][E])
    u16*   wf2t = wf1t + (size_t)L_ * E_ * FF_;   // 6 * 512*2048 (as [E][FF])
    u16*   wqt  = wf2t + (size_t)L_ * FF_ * E_;   // 6 * 64*64
    u16*   wkt  = wqt + (size_t)L_ * HD_ * HD_;
    u16*   wvt  = wkt + (size_t)L_ * HD_ * HD_;
    u16*   wft  = wvt + (size_t)L_ * HD_ * HD_;   // 64*512  (Wfin as [O][E])
    u16*   w1t  = wft + (size_t)O_ * E_;          // 512*64  (W_first as [E][F])

    const int rows = N_ * S_;                     // 8192

    wprep<<<32 + 1536 + 12288 + 32 + 6, 256, 0, stream>>>(
        W_first, Wo, Wf1, Wf2, Wfin, Wq, Wk, Wv,
        w1t, wot, wf1t, wf2t, wft, wqt, wkt, wvt);

    first_mfma<<<dim3(E_ / 128, rows / 128), 256, 0, stream>>>(
        x, w1t, b_first, pos_emb, resb);

    for (int i = 0; i < L_; i++) {
        qkv_mfma<<<512, 256, 0, stream>>>(
            resb, wqt + (size_t)i * HD_ * HD_, wkt + (size_t)i * HD_ * HD_,
            wvt + (size_t)i * HD_ * HD_, bq + i * HD_, bk + i * HD_, bv + i * HD_,
            qb, kb, vt);
        attn_mfma<<<512, 512, 0, stream>>>(qb, kb, vt, ob);
        // t1 = ob @ Wo + bo + resb(h)   [PIPE3 counted-vmcnt]
        gemm_mfma<128, 64, true, false, true, true, false><<<dim3(E_ / 64, rows / 128), 256, 0, stream>>>(
            ob, wot + (size_t)i * E_ * E_, bo + i * E_, resb, t1, nullptr, rows, E_, E_);
        layernorm_k<<<rows, 256, 0, stream>>>(t1, g1 + i * E_, be1 + i * E_, resb);
        // ffb = relu(resb(hx) @ Wf1 + bf1)   [2-buffer path]
        gemm_mfma<128, 128, false, true, false, false, true><<<dim3(FF_ / 128, rows / 128), 256, 0, stream>>>(
            resb, wf1t + (size_t)i * E_ * FF_, bf1 + i * FF_, nullptr, nullptr, ffb,
            rows, FF_, E_);
        // t1 = ffb @ Wf2 + bf2 + resb(hx)   [PIPE3 counted-vmcnt]
        gemm_mfma<128, 64, true, false, true, true, false><<<dim3(E_ / 64, rows / 128), 256, 0, stream>>>(
            ffb, wf2t + (size_t)i * FF_ * E_, bf2 + i * E_, resb, t1, nullptr,
            rows, E_, FF_);
        layernorm_k<<<rows, 256, 0, stream>>>(t1, g2 + i * E_, be2 + i * E_, resb);
    }

    final_mfma<<<rows / 64, 256, 0, stream>>>(resb, wft, bfin, out);
}

// Round 9
// 932.344 us; speedup vs baseline: 1.5668x; 1.0276x over previous
//
#include <hip/hip_runtime.h>
#include <hip/hip_bf16.h>
#include <math.h>

// Problem constants
#define N_ 8
#define S_ 1024
#define F_ 64
#define E_ 512
#define H_ 8
#define O_ 64
#define L_ 6
#define HD_ 64
#define FF_ 2048
#define SCALE_ 0.044194173824159216f   // 1/sqrt(E) -- module scales by sqrt(embed_size)
#define LOG2E_ 1.4426950408889634f
#define QSCALE_ (SCALE_ * LOG2E_)      // folded into Q at projection time

typedef unsigned short u16;
typedef __attribute__((ext_vector_type(4))) unsigned short u16x4;
typedef __attribute__((ext_vector_type(8))) unsigned short u16x8;
typedef __attribute__((ext_vector_type(8))) short short8;
typedef __attribute__((ext_vector_type(4))) float floatx4;

__device__ __forceinline__ u16 f2b(float f) {          // RNE (weights, one-time)
    union { float f; unsigned u; } v; v.f = f;
    unsigned u = v.u;
    unsigned r = (u + 0x7FFFu + ((u >> 16) & 1u)) >> 16;
    return (u16)r;
}
__device__ __forceinline__ u16 f2b_fast(float f) {     // round-nearest, 2 ops
    union { float f; unsigned u; } v; v.f = f;
    return (u16)((v.u + 0x8000u) >> 16);
}
__device__ __forceinline__ float b2f(u16 h) {
    union { unsigned u; float f; } v; v.u = ((unsigned)h) << 16;
    return v.f;
}

// async global->LDS, 16B per lane. LDS dest is wave-uniform base + lane*16.
__device__ __forceinline__ void gload16(const u16* g, u16* l) {
    __builtin_amdgcn_global_load_lds(
        (const __attribute__((address_space(1))) void*)g,
        (__attribute__((address_space(3))) void*)l, 16, 0, 0);
}

// ---------------------------------------------------------------------------
// MFMA first projection: h = relu(x^T W + b) + pos -> bf16 residual stream.
__global__ __launch_bounds__(256) void first_mfma(
    const float* __restrict__ x, const u16* __restrict__ wt,
    const float* __restrict__ bf, const float* __restrict__ pe,
    u16* __restrict__ resb)
{
    __shared__ u16 a_s[128][72];
    int t = threadIdx.x;
    int w = t >> 6, lane = t & 63, quad = lane >> 4, c16 = lane & 15;
    int rowhalf = w >> 1, colhalf = w & 1;
    int col0 = blockIdx.x * 128;
    int row0 = blockIdx.y * 128;          // n*S + s0 (never crosses n)
    int n = row0 >> 10, s0 = row0 & 1023;

    const float* xb = x + (size_t)n * F_ * S_ + s0;
    #pragma unroll
    for (int i = 0; i < 8; i++) {
        int pos = (t + i * 256) * 4;      // 8192 elems, f-major
        int f = pos >> 7, sl = pos & 127;
        float4 v = *(const float4*)&xb[(size_t)f * S_ + sl];
        a_s[sl + 0][f] = f2b_fast(v.x);
        a_s[sl + 1][f] = f2b_fast(v.y);
        a_s[sl + 2][f] = f2b_fast(v.z);
        a_s[sl + 3][f] = f2b_fast(v.w);
    }
    __syncthreads();

    floatx4 acc[4][4];
    #pragma unroll
    for (int mt = 0; mt < 4; mt++)
        #pragma unroll
        for (int nt = 0; nt < 4; nt++) acc[mt][nt] = (floatx4){0.f, 0.f, 0.f, 0.f};

    #pragma unroll
    for (int ks = 0; ks < 2; ks++) {
        short8 af[4], bfr[4];
        #pragma unroll
        for (int mt = 0; mt < 4; mt++)
            af[mt] = *(const short8*)&a_s[rowhalf * 64 + mt * 16 + c16][ks * 32 + quad * 8];
        #pragma unroll
        for (int nt = 0; nt < 4; nt++)
            bfr[nt] = *(const short8*)&wt[(size_t)(col0 + colhalf * 64 + nt * 16 + c16) * F_
                                          + ks * 32 + quad * 8];
        #pragma unroll
        for (int mt = 0; mt < 4; mt++)
            #pragma unroll
            for (int nt = 0; nt < 4; nt++)
                acc[mt][nt] = __builtin_amdgcn_mfma_f32_16x16x32_bf16(
                    af[mt], bfr[nt], acc[mt][nt], 0, 0, 0);
    }

    #pragma unroll
    for (int nt = 0; nt < 4; nt++) {
        int col = col0 + colhalf * 64 + nt * 16 + c16;
        float bv = bf[col];
        #pragma unroll
        for (int mt = 0; mt < 4; mt++) {
            #pragma unroll
            for (int r = 0; r < 4; r++) {
                size_t row = (size_t)row0 + rowhalf * 64 + mt * 16 + quad * 4 + r;
                int s = (int)(row & 1023);
                float v = fmaxf(acc[mt][nt][r] + bv, 0.f) + pe[(size_t)s * E_ + col];
                resb[row * E_ + col] = f2b_fast(v);
            }
        }
    }
}

// ---------------------------------------------------------------------------
// ONE-launch weight prep: all cast+transposes + qkv weights, dispatched by
// blockIdx range. Replaces 6 separate launches.
__global__ __launch_bounds__(256) void wprep(
    const float* __restrict__ W_first, const float* __restrict__ Wo,
    const float* __restrict__ Wf1, const float* __restrict__ Wf2,
    const float* __restrict__ Wfin,
    const float* __restrict__ Wq, const float* __restrict__ Wk,
    const float* __restrict__ Wv,
    u16* __restrict__ w1t, u16* __restrict__ wot, u16* __restrict__ wf1t,
    u16* __restrict__ wf2t, u16* __restrict__ wft,
    u16* __restrict__ wqt, u16* __restrict__ wkt, u16* __restrict__ wvt)
{
    int b = blockIdx.x;
    int t = threadIdx.x;
    __shared__ float tile[32][33];
    const float* W; u16* Wt; int K, Nc, bx, by;
    if (b < 32) {                         // W_first: K=64, Nc=512
        W = W_first; Wt = w1t; K = F_; Nc = E_; bx = b & 15; by = b >> 4;
    } else if (b < 32 + 1536) {           // Wo x6: K=512, Nc=512
        int i = b - 32; int z = i >> 8; int r = i & 255;
        W = Wo + (size_t)z * E_ * E_; Wt = wot + (size_t)z * E_ * E_;
        K = E_; Nc = E_; bx = r & 15; by = r >> 4;
    } else if (b < 32 + 1536 + 6144) {    // Wf1 x6: K=512, Nc=2048
        int i = b - (32 + 1536); int z = i >> 10; int r = i & 1023;
        W = Wf1 + (size_t)z * E_ * FF_; Wt = wf1t + (size_t)z * E_ * FF_;
        K = E_; Nc = FF_; bx = r & 63; by = r >> 6;
    } else if (b < 32 + 1536 + 12288) {   // Wf2 x6: K=2048, Nc=512
        int i = b - (32 + 1536 + 6144); int z = i >> 10; int r = i & 1023;
        W = Wf2 + (size_t)z * FF_ * E_; Wt = wf2t + (size_t)z * FF_ * E_;
        K = FF_; Nc = E_; bx = r & 15; by = r >> 4;
    } else if (b < 32 + 1536 + 12288 + 32) { // Wfin: K=512, Nc=64
        int r = b - (32 + 1536 + 12288);
        W = Wfin; Wt = wft; K = E_; Nc = O_; bx = r & 1; by = r >> 1;
    } else {                              // qkv weights: 6 blocks (1/layer)
        int l = b - (32 + 1536 + 12288 + 32);
        size_t off = (size_t)l * HD_ * HD_;
        #pragma unroll
        for (int i = 0; i < 16; i++) {
            int idx = t + i * 256;        // = e*64 + d
            int e = idx >> 6, d = idx & 63;
            wqt[off + idx] = f2b(Wq[off + d * HD_ + e]);
            wkt[off + idx] = f2b(Wk[off + d * HD_ + e]);
            wvt[off + idx] = f2b(Wv[off + d * HD_ + e]);
        }
        return;
    }
    #pragma unroll
    for (int i = 0; i < 4; i++) {
        int q = t + i * 256; int r = q >> 5, c = q & 31;
        tile[r][c] = W[(size_t)(by * 32 + r) * Nc + bx * 32 + c];
    }
    __syncthreads();
    #pragma unroll
    for (int i = 0; i < 4; i++) {
        int q = t + i * 256; int r = q >> 5, c = q & 31;
        Wt[(size_t)(bx * 32 + r) * K + by * 32 + c] = f2b(tile[c][r]);
    }
}

// ---------------------------------------------------------------------------
// MFMA fused qkv; Q pre-scaled by QSCALE_; V written DIRECTLY transposed
// (N,H,D,S) via LDS re-transpose. A-fragments read DIRECT from global
// (rows are 128B, row-contiguous across lanes -> coalesced, L2-served).
__global__ __launch_bounds__(256) void qkv_mfma(
    const u16* __restrict__ hb,
    const u16* __restrict__ wqt, const u16* __restrict__ wkt,
    const u16* __restrict__ wvt,
    const float* __restrict__ bq, const float* __restrict__ bk,
    const float* __restrict__ bvp,
    u16* __restrict__ qo, u16* __restrict__ ko, u16* __restrict__ vt)
{
    __shared__ u16 vt_s[128 * 64];       // only for the V transpose
    int t = threadIdx.x;
    int w = t >> 6, lane = t & 63, quad = lane >> 4, c16 = lane & 15;
    size_t row0 = (size_t)blockIdx.x * 128;

    short8 af[2][2];
    #pragma unroll
    for (int mt = 0; mt < 2; mt++)
        #pragma unroll
        for (int ks = 0; ks < 2; ks++)
            af[mt][ks] = *(const short8*)&hb[(row0 + w * 32 + mt * 16 + c16) * HD_
                                             + ks * 32 + quad * 8];

    // ---- Q (m=0) and K (m=1): normal row-major stores --------------------
    const u16* wts[2] = {wqt, wkt};
    const float* bs[2] = {bq, bk};
    u16* outs[2] = {qo, ko};
    #pragma unroll
    for (int m = 0; m < 2; m++) {
        short8 bfr[4][2];
        #pragma unroll
        for (int nt = 0; nt < 4; nt++)
            #pragma unroll
            for (int ks = 0; ks < 2; ks++)
                bfr[nt][ks] = *(const short8*)&wts[m][(nt * 16 + c16) * HD_ + ks * 32 + quad * 8];
        floatx4 acc[2][4];
        #pragma unroll
        for (int mt = 0; mt < 2; mt++)
            #pragma unroll
            for (int nt = 0; nt < 4; nt++) acc[mt][nt] = (floatx4){0.f, 0.f, 0.f, 0.f};
        #pragma unroll
        for (int ks = 0; ks < 2; ks++)
            #pragma unroll
            for (int mt = 0; mt < 2; mt++)
                #pragma unroll
                for (int nt = 0; nt < 4; nt++)
                    acc[mt][nt] = __builtin_amdgcn_mfma_f32_16x16x32_bf16(
                        af[mt][ks], bfr[nt][ks], acc[mt][nt], 0, 0, 0);
        float osc = (m == 0) ? QSCALE_ : 1.0f;
        #pragma unroll
        for (int nt = 0; nt < 4; nt++) {
            float bv_ = bs[m][nt * 16 + c16];
            #pragma unroll
            for (int mt = 0; mt < 2; mt++)
                #pragma unroll
                for (int r = 0; r < 4; r++)
                    outs[m][(row0 + w * 32 + mt * 16 + quad * 4 + r) * HD_ + nt * 16 + c16] =
                        f2b_fast((acc[mt][nt][r] + bv_) * osc);
        }
    }

    // ---- V (m=2): compute, then transpose via LDS to (N,H,D,S) -----------
    {
        short8 bfr[4][2];
        #pragma unroll
        for (int nt = 0; nt < 4; nt++)
            #pragma unroll
            for (int ks = 0; ks < 2; ks++)
                bfr[nt][ks] = *(const short8*)&wvt[(nt * 16 + c16) * HD_ + ks * 32 + quad * 8];
        floatx4 acc[2][4];
        #pragma unroll
        for (int mt = 0; mt < 2; mt++)
            #pragma unroll
            for (int nt = 0; nt < 4; nt++) acc[mt][nt] = (floatx4){0.f, 0.f, 0.f, 0.f};
        #pragma unroll
        for (int ks = 0; ks < 2; ks++)
            #pragma unroll
            for (int mt = 0; mt < 2; mt++)
                #pragma unroll
                for (int nt = 0; nt < 4; nt++)
                    acc[mt][nt] = __builtin_amdgcn_mfma_f32_16x16x32_bf16(
                        af[mt][ks], bfr[nt][ks], acc[mt][nt], 0, 0, 0);

        #pragma unroll
        for (int nt = 0; nt < 4; nt++) {
            float bv_ = bvp[nt * 16 + c16];
            #pragma unroll
            for (int mt = 0; mt < 2; mt++)
                #pragma unroll
                for (int r = 0; r < 4; r++) {
                    int fr = w * 32 + mt * 16 + quad * 4 + r;   // flat row in block
                    int h = fr & 7, sl = fr >> 3;
                    vt_s[((h * 64 + nt * 16 + c16) * 16) + sl] =
                        f2b_fast(acc[mt][nt][r] + bv_);
                }
        }
        __syncthreads();
        int sflat0 = (int)(row0 >> 3);   // 16-aligned; same n for whole block
        int n = sflat0 >> 10, sbase = sflat0 & 1023;
        #pragma unroll
        for (int i = 0; i < 4; i++) {
            int u = t + i * 256;         // 1024 units of 16B
            int h = u >> 7, rest = u & 127, d = rest >> 1, half = rest & 1;
            *(u16x8*)&vt[((size_t)((n * 8 + h) * 64 + d)) * (size_t)S_ + sbase + half * 8] =
                *(u16x8*)&vt_s[(h * 64 + d) * 16 + half * 8];
        }
    }
}

// ---------------------------------------------------------------------------
// MFMA flash attention: QBLK=128 with 512 threads / 8 waves (16-row q-strips)
// -> 4 waves/SIMD at identical grid+HBM traffic (latency chain hidden by TLP).
// Double-buffered K/V, ONE barrier per k-tile, XOR-swizzled stride-64 LDS,
// setprio, chunked bid swizzle. 48KB LDS, grid 512.
__global__ __launch_bounds__(512, 4) void attn_mfma(
    const u16* __restrict__ Q, const u16* __restrict__ K,
    const u16* __restrict__ Vt, u16* __restrict__ O)
{
    int bid0 = blockIdx.x;               // 512 = N*H*(S/128)
    int bid = (bid0 & 7) * 64 + (bid0 >> 3);    // chunked XCD swizzle
    int qt = bid & 7, hh = (bid >> 3) & 7, n = bid >> 6;
    int t = threadIdx.x;
    int w = t >> 6, lane = t & 63, quad = lane >> 4, c16 = lane & 15;

    __shared__ u16 qp_s[128 * 64];       // Q tile; 8x16-row P strips alias it
    __shared__ u16 k_s[2][64 * 64];      // K rows (key, d), double-buffered
    __shared__ u16 vt_s[2][64 * 64];     // Vt rows (d, key), double-buffered
    u16* p_s = qp_s + w * 16 * 64;       // wave-private 16-row strip

    const size_t qkbase = (size_t)n * S_ * E_ + hh * 64;
    const size_t vtbase = ((size_t)(n * H_ + hh) * 64) * (size_t)S_;

    int ar = t >> 3, act = t & 7;        // 64 rows x 8 chunks = 512 threads
    int acq = act * 8;
    int scw = (act ^ (ar & 7)) * 8;

    // Q staging (128 rows x 8 chunks, 2 iters) + KV tile-0 register load
    #pragma unroll
    for (int i = 0; i < 2; i++) {
        int q = t + i * 512; int r = q >> 3, c = q & 7;
        *(u16x8*)&qp_s[r * 64 + ((c ^ (r & 7)) * 8)] =
            *(const u16x8*)&Q[qkbase + (size_t)(qt * 128 + r) * E_ + c * 8];
    }
    u16x8 pk = *(const u16x8*)&K[qkbase + (size_t)ar * E_ + acq];
    u16x8 pv = *(const u16x8*)&Vt[vtbase + (size_t)ar * S_ + acq];
    __syncthreads();                     // Q visible

    // hoist Q fragments (B-operand of S^T): q row w*16 + c16
    short8 qf[2];
    #pragma unroll
    for (int ks = 0; ks < 2; ks++) {
        int r = w * 16 + c16;
        qf[ks] = *(const short8*)&qp_s[r * 64 + (((ks * 4 + quad) ^ (r & 7)) * 8)];
    }

    // write tile 0 into buffer 0
    *(u16x8*)&k_s[0][ar * 64 + scw] = pk;
    *(u16x8*)&vt_s[0][ar * 64 + scw] = pv;
    __syncthreads();                     // tile 0 visible; all qf hoisted

    const short8 ones = {(short)0x3F80, (short)0x3F80, (short)0x3F80, (short)0x3F80,
                         (short)0x3F80, (short)0x3F80, (short)0x3F80, (short)0x3F80};

    floatx4 oaccT[4];                    // [d-tile]: O^T[d][q]
    floatx4 lacc = (floatx4){0.f, 0.f, 0.f, 0.f};
    #pragma unroll
    for (int mt = 0; mt < 4; mt++) oaccT[mt] = (floatx4){0.f, 0.f, 0.f, 0.f};

    for (int k0 = 0; k0 < S_; k0 += 64) {
        int cur = (k0 >> 6) & 1;
        const u16* ks_ = k_s[cur];
        const u16* vs_ = vt_s[cur];
        bool more = (k0 + 64 < S_);
        if (more) {                      // issue next-tile loads early
            pk = *(const u16x8*)&K[qkbase + (size_t)(k0 + 64 + ar) * E_ + acq];
            pv = *(const u16x8*)&Vt[vtbase + (size_t)ar * S_ + k0 + 64 + acq];
        }

        // S^T = K Q^T : st[mt], lane holds S[q=c16][key=mt*16+quad*4+r]
        floatx4 st[4];
        #pragma unroll
        for (int mt = 0; mt < 4; mt++) st[mt] = (floatx4){0.f, 0.f, 0.f, 0.f};
        __builtin_amdgcn_s_setprio(1);
        #pragma unroll
        for (int ks = 0; ks < 2; ks++) {
            short8 kf[4];
            #pragma unroll
            for (int mt = 0; mt < 4; mt++) {
                int r = mt * 16 + c16;
                kf[mt] = *(const short8*)&ks_[r * 64 + (((ks * 4 + quad) ^ (r & 7)) * 8)];
            }
            #pragma unroll
            for (int mt = 0; mt < 4; mt++)
                st[mt] = __builtin_amdgcn_mfma_f32_16x16x32_bf16(
                    kf[mt], qf[ks], st[mt], 0, 0, 0);
        }
        __builtin_amdgcn_s_setprio(0);

        // P = exp2(S^T), pack 4 keys -> one b64 swizzled LDS write per mt
        #pragma unroll
        for (int mt = 0; mt < 4; mt++) {
            u16x4 h;
            #pragma unroll
            for (int r = 0; r < 4; r++) h[r] = f2b_fast(exp2f(st[mt][r]));
            *(u16x4*)&p_s[c16 * 64 + (((2 * mt + (quad >> 1)) ^ (c16 & 7)) * 8)
                          + (quad & 1) * 4] = h;
        }

        // O^T += V^T P^T ; l += ones . P^T   (p_s wave-private: no barrier)
        __builtin_amdgcn_s_setprio(1);
        #pragma unroll
        for (int ks = 0; ks < 2; ks++) {
            short8 pf = *(const short8*)&p_s[c16 * 64 + (((ks * 4 + quad) ^ (c16 & 7)) * 8)];
            short8 vf[4];
            #pragma unroll
            for (int mt = 0; mt < 4; mt++) {
                int r = mt * 16 + c16;
                vf[mt] = *(const short8*)&vs_[r * 64 + (((ks * 4 + quad) ^ (r & 7)) * 8)];
            }
            lacc = __builtin_amdgcn_mfma_f32_16x16x32_bf16(ones, pf, lacc, 0, 0, 0);
            #pragma unroll
            for (int mt = 0; mt < 4; mt++)
                oaccT[mt] = __builtin_amdgcn_mfma_f32_16x16x32_bf16(
                    vf[mt], pf, oaccT[mt], 0, 0, 0);
        }
        __builtin_amdgcn_s_setprio(0);

        if (more) {                      // stage next tile into the other buffer
            *(u16x8*)&k_s[cur ^ 1][ar * 64 + scw] = pk;
            *(u16x8*)&vt_s[cur ^ 1][ar * 64 + scw] = pv;
        }
        __syncthreads();                 // next buffer ready; this one reusable
    }

    // epilogue: lane c16 owns q-row; 4 contiguous d per (mt) -> 8B stores
    {
        float rl = 1.f / lacc[0];
        int s = qt * 128 + w * 16 + c16;
        size_t base = (size_t)(n * S_ + s) * E_ + hh * 64;
        #pragma unroll
        for (int mt = 0; mt < 4; mt++) {
            u16x4 h;
            #pragma unroll
            for (int r = 0; r < 4; r++) h[r] = f2b_fast(oaccT[mt][r] * rl);
            *(u16x4*)&O[base + mt * 16 + quad * 4] = h;
        }
    }
}

// ---------------------------------------------------------------------------
// MFMA GEMM, m97 structure: SINGLE-buffer async global_load_lds staging,
// 2 barriers per K-step, 24-32 KB LDS, __launch_bounds__(256,3) -> 3
// blocks/CU (12 waves/CU). Inter-block wave overlap hides the barrier
// drains (m114/m97 mechanism) -- intra-block pipelining (rounds 7-8) was
// neutral at 2 blocks/CU, so this trades LDS for occupancy instead.
// ds_read swizzle via pre-swizzled global source (rule #21); chunked XCD
// swizzle colocates same-A-panel blocks on one XCD's L2.
template <int MT, int NT, bool RELU, bool HASRES, bool OUTF32, bool OUTBF16>
__global__ __launch_bounds__(256, 3) void gemm_mfma(
    const u16* __restrict__ A, const u16* __restrict__ Bt,
    const float* __restrict__ bias, const u16* __restrict__ resid,
    float* __restrict__ outf, u16* __restrict__ outb, int M, int Nc, int K)
{
    constexpr int MFR = MT / 32;
    constexpr int NFR = NT / 32;
    constexpr int AI  = MT / 32;
    constexpr int BI  = NT / 32;
    __shared__ u16 a_s[MT * 64];
    __shared__ u16 b_s[NT * 64];

    int t = threadIdx.x;
    int w = t >> 6, lane = t & 63, quad = lane >> 4, c16 = lane & 15;
    int rw = w >> 1, cw = w & 1;

    int gx = gridDim.x;
    int nwg = gx * (int)gridDim.y;
    int lin = (int)blockIdx.y * gx + (int)blockIdx.x;
    int cpx = nwg >> 3;
    int id2 = (lin & 7) * cpx + (lin >> 3);
    int bx = id2 % gx, by = id2 / gx;

    size_t row0 = (size_t)by * MT;
    size_t col0 = (size_t)bx * NT;

    size_t aoff[AI]; int adst[AI];
    #pragma unroll
    for (int i = 0; i < AI; i++) {
        int p = t + i * 256;
        int r = p >> 3;
        int kc = (p & 7) ^ (r & 7);
        aoff[i] = (row0 + r) * (size_t)K + kc * 8;
        adst[i] = w * 512 + i * 2048;
    }
    size_t boff[BI]; int bdst[BI];
    #pragma unroll
    for (int i = 0; i < BI; i++) {
        int p = t + i * 256;
        int r = p >> 3;
        int kc = (p & 7) ^ (r & 7);
        boff[i] = (col0 + r) * (size_t)K + kc * 8;
        bdst[i] = w * 512 + i * 2048;
    }

    floatx4 acc[MFR][NFR];
    #pragma unroll
    for (int mt = 0; mt < MFR; mt++)
        #pragma unroll
        for (int nt = 0; nt < NFR; nt++) acc[mt][nt] = (floatx4){0.f, 0.f, 0.f, 0.f};

    for (int k0 = 0; k0 < K; k0 += 64) {
        #pragma unroll
        for (int i = 0; i < AI; i++) gload16(A + aoff[i] + k0, a_s + adst[i]);
        #pragma unroll
        for (int i = 0; i < BI; i++) gload16(Bt + boff[i] + k0, b_s + bdst[i]);
        __syncthreads();               // drains vmcnt(0): tile landed in LDS

        #pragma unroll
        for (int ks = 0; ks < 2; ks++) {
            short8 af[MFR], bfr[NFR];
            #pragma unroll
            for (int mt = 0; mt < MFR; mt++) {
                int r = rw * (MT / 2) + mt * 16 + c16;
                af[mt] = *(const short8*)&a_s[r * 64 + (((ks * 4 + quad) ^ (r & 7)) * 8)];
            }
            #pragma unroll
            for (int nt = 0; nt < NFR; nt++) {
                int r = cw * (NT / 2) + nt * 16 + c16;
                bfr[nt] = *(const short8*)&b_s[r * 64 + (((ks * 4 + quad) ^ (r & 7)) * 8)];
            }
            #pragma unroll
            for (int mt = 0; mt < MFR; mt++)
                #pragma unroll
                for (int nt = 0; nt < NFR; nt++)
                    acc[mt][nt] = __builtin_amdgcn_mfma_f32_16x16x32_bf16(
                        af[mt], bfr[nt], acc[mt][nt], 0, 0, 0);
        }
        __syncthreads();               // all reads done before next stage
    }

    #pragma unroll
    for (int nt = 0; nt < NFR; nt++) {
        int col = (int)col0 + cw * (NT / 2) + nt * 16 + c16;
        float bv = bias[col];
        #pragma unroll
        for (int mt = 0; mt < MFR; mt++) {
            size_t rowb = row0 + rw * (MT / 2) + mt * 16 + quad * 4;
            #pragma unroll
            for (int r = 0; r < 4; r++) {
                size_t row = rowb + r;
                float v = acc[mt][nt][r] + bv;
                if constexpr (HASRES) v += b2f(resid[row * Nc + col]);
                if constexpr (RELU) v = fmaxf(v, 0.f);
                if constexpr (OUTF32) outf[row * Nc + col] = v;
                if constexpr (OUTBF16) outb[row * Nc + col] = f2b_fast(v);
            }
        }
    }
}

// ---------------------------------------------------------------------------
// LayerNorm over E=512, one block per row; fp32 in, bf16 out.
// float2-vectorized loads (G13), packed 4B bf16x2 stores.
__global__ __launch_bounds__(256) void layernorm_k(
    const float* __restrict__ in, const float* __restrict__ g,
    const float* __restrict__ bb, u16* __restrict__ outb)
{
    int row = blockIdx.x;
    int t = threadIdx.x;
    const float* x = in + (size_t)row * E_;
    float2 xv = *(const float2*)&x[t * 2];
    float s = xv.x + xv.y;
    #pragma unroll
    for (int off = 32; off; off >>= 1) s += __shfl_down(s, off, 64);
    __shared__ float red[4];
    int wid = t >> 6, lane = t & 63;
    if (lane == 0) red[wid] = s;
    __syncthreads();
    float m = (red[0] + red[1] + red[2] + red[3]) * (1.f / E_);
    float d0 = xv.x - m, d1 = xv.y - m;
    float sq = d0 * d0 + d1 * d1;
    #pragma unroll
    for (int off = 32; off; off >>= 1) sq += __shfl_down(sq, off, 64);
    __syncthreads();
    if (lane == 0) red[wid] = sq;
    __syncthreads();
    float var = (red[0] + red[1] + red[2] + red[3]) * (1.f / E_);
    float rstd = rsqrtf(var + 1e-5f);
    float2 gv = *(const float2*)&g[t * 2];
    float2 bv = *(const float2*)&bb[t * 2];
    unsigned o = (unsigned)f2b_fast(d0 * rstd * gv.x + bv.x)
               | ((unsigned)f2b_fast(d1 * rstd * gv.y + bv.y) << 16);
    *(unsigned*)&outb[(size_t)row * E_ + t * 2] = o;
}

// ---------------------------------------------------------------------------
// MFMA final projection: out[n,o,s] = resb[n*S+s,:] @ Wfint[o,:] + bfin[o]
__global__ __launch_bounds__(256) void final_mfma(
    const u16* __restrict__ hb, const u16* __restrict__ wft,
    const float* __restrict__ bfin, float* __restrict__ outp)
{
    __shared__ u16 a_s[64][72];
    int t = threadIdx.x;
    int w = t >> 6, lane = t & 63, quad = lane >> 4, c16 = lane & 15;
    size_t row0 = (size_t)blockIdx.x * 64;

    floatx4 acc[4];
    #pragma unroll
    for (int nt = 0; nt < 4; nt++) acc[nt] = (floatx4){0.f, 0.f, 0.f, 0.f};

    int ar = t >> 3, acq = (t & 7) * 8;
    u16x8 pa[2];
    #pragma unroll
    for (int i = 0; i < 2; i++)
        pa[i] = *(const u16x8*)&hb[(row0 + ar + i * 32) * E_ + acq];

    for (int k0 = 0; k0 < E_; k0 += 64) {
        #pragma unroll
        for (int i = 0; i < 2; i++)
            *(u16x8*)&a_s[ar + i * 32][acq] = pa[i];
        __syncthreads();
        if (k0 + 64 < E_) {
            #pragma unroll
            for (int i = 0; i < 2; i++)
                pa[i] = *(const u16x8*)&hb[(row0 + ar + i * 32) * E_ + k0 + 64 + acq];
        }
        #pragma unroll
        for (int ks = 0; ks < 2; ks++) {
            short8 af = *(const short8*)&a_s[w * 16 + c16][ks * 32 + quad * 8];
            #pragma unroll
            for (int nt = 0; nt < 4; nt++) {
                short8 bf = *(const short8*)&wft[(nt * 16 + c16) * E_ + k0 + ks * 32 + quad * 8];
                acc[nt] = __builtin_amdgcn_mfma_f32_16x16x32_bf16(af, bf, acc[nt], 0, 0, 0);
            }
        }
        __syncthreads();
    }

    #pragma unroll
    for (int nt = 0; nt < 4; nt++) {
        int o = nt * 16 + c16;
        float bv = bfin[o];
        #pragma unroll
        for (int r = 0; r < 4; r++) {
            size_t row = row0 + w * 16 + quad * 4 + r;    // n*S + s
            int n = (int)(row >> 10), s = (int)(row & 1023);
            outp[((size_t)(n * O_ + o)) * S_ + s] = acc[nt][r] + bv;
        }
    }
}

// ---------------------------------------------------------------------------
extern "C" void kernel_launch(void* const* d_in, const int* in_sizes, int n_in,
                              void* d_out, int out_size, void* d_ws, size_t ws_size,
                              hipStream_t stream)
{
    const float* x       = (const float*)d_in[0];
    const float* W_first = (const float*)d_in[1];
    const float* b_first = (const float*)d_in[2];
    const float* pos_emb = (const float*)d_in[3];
    const float* Wq      = (const float*)d_in[4];
    const float* bq      = (const float*)d_in[5];
    const float* Wk      = (const float*)d_in[6];
    const float* bk      = (const float*)d_in[7];
    const float* Wv      = (const float*)d_in[8];
    const float* bv      = (const float*)d_in[9];
    const float* Wo      = (const float*)d_in[10];
    const float* bo      = (const float*)d_in[11];
    const float* g1      = (const float*)d_in[12];
    const float* be1     = (const float*)d_in[13];
    const float* Wf1     = (const float*)d_in[14];
    const float* bf1     = (const float*)d_in[15];
    const float* Wf2     = (const float*)d_in[16];
    const float* bf2     = (const float*)d_in[17];
    const float* g2      = (const float*)d_in[18];
    const float* be2     = (const float*)d_in[19];
    const float* Wfin    = (const float*)d_in[20];
    const float* bfin    = (const float*)d_in[21];
    float* out = (float*)d_out;

    const size_t M4 = (size_t)N_ * S_ * E_;       // 4,194,304
    float* t1   = (float*)d_ws;                   // fp32 LN input
    u16*   resb = (u16*)(t1 + M4);                // bf16 residual stream (h/hx)
    u16*   qb   = resb + M4;
    u16*   kb   = qb + M4;
    u16*   vt   = kb + M4;
    u16*   ob   = vt + M4;
    u16*   ffb  = qb;                             // alias qb..ob (4*M4 = 32MB)
    u16*   wot  = ob + M4;                        // 6 * 512*512
    u16*   wf1t = wot + (size_t)L_ * E_ * E_;     // 6 * 2048*512 (as [FF][E])
    u16*   wf2t = wf1t + (size_t)L_ * E_ * FF_;   // 6 * 512*2048 (as [E][FF])
    u16*   wqt  = wf2t + (size_t)L_ * FF_ * E_;   // 6 * 64*64
    u16*   wkt  = wqt + (size_t)L_ * HD_ * HD_;
    u16*   wvt  = wkt + (size_t)L_ * HD_ * HD_;
    u16*   wft  = wvt + (size_t)L_ * HD_ * HD_;   // 64*512  (Wfin as [O][E])
    u16*   w1t  = wft + (size_t)O_ * E_;          // 512*64  (W_first as [E][F])

    const int rows = N_ * S_;                     // 8192

    wprep<<<32 + 1536 + 12288 + 32 + 6, 256, 0, stream>>>(
        W_first, Wo, Wf1, Wf2, Wfin, Wq, Wk, Wv,
        w1t, wot, wf1t, wf2t, wft, wqt, wkt, wvt);

    first_mfma<<<dim3(E_ / 128, rows / 128), 256, 0, stream>>>(
        x, w1t, b_first, pos_emb, resb);

    for (int i = 0; i < L_; i++) {
        qkv_mfma<<<512, 256, 0, stream>>>(
            resb, wqt + (size_t)i * HD_ * HD_, wkt + (size_t)i * HD_ * HD_,
            wvt + (size_t)i * HD_ * HD_, bq + i * HD_, bk + i * HD_, bv + i * HD_,
            qb, kb, vt);
        attn_mfma<<<512, 512, 0, stream>>>(qb, kb, vt, ob);
        // t1 = ob @ Wo + bo + resb(h)
        gemm_mfma<128, 64, false, true, true, false><<<dim3(E_ / 64, rows / 128), 256, 0, stream>>>(
            ob, wot + (size_t)i * E_ * E_, bo + i * E_, resb, t1, nullptr, rows, E_, E_);
        layernorm_k<<<rows, 256, 0, stream>>>(t1, g1 + i * E_, be1 + i * E_, resb);
        // ffb = relu(resb(hx) @ Wf1 + bf1)
        gemm_mfma<128, 128, true, false, false, true><<<dim3(FF_ / 128, rows / 128), 256, 0, stream>>>(
            resb, wf1t + (size_t)i * E_ * FF_, bf1 + i * FF_, nullptr, nullptr, ffb,
            rows, FF_, E_);
        // t1 = ffb @ Wf2 + bf2 + resb(hx)
        gemm_mfma<128, 64, false, true, true, false><<<dim3(E_ / 64, rows / 128), 256, 0, stream>>>(
            ffb, wf2t + (size_t)i * FF_ * E_, bf2 + i * E_, resb, t1, nullptr,
            rows, E_, FF_);
        layernorm_k<<<rows, 256, 0, stream>>>(t1, g2 + i * E_, be2 + i * E_, resb);
    }

    final_mfma<<<rows / 64, 256, 0, stream>>>(resb, wft, bfin, out);
}